// Round 1
// baseline (2199.829 us; speedup 1.0000x reference)
//
#include <hip/hip_runtime.h>
#include <hip/hip_bf16.h>

#define MODS 3
#define BSZ 2
#define LSEQ 2048
#define DMODEL 512
#define DINNER 1024
#define DTRANK 32
#define NSTATE 16
#define DCONV 4
#define MROWS (BSZ*LSEQ)   // 4096

// ---------------- GEMM NT: C[z] = res[z] + alpha * act(A[z] @ B[z]^T + bias[z]) ----------------
// A: [M,K] lda, B: [N,K] ldb (row-major, NT), C: [M,N] ldc. act: 0=none, 1=softplus.
// All of M,N divisible by 64 and K divisible by 16 in every use — no bounds checks.
__global__ __launch_bounds__(256) void gemm_nt_kernel(
    const float* __restrict__ A, const float* __restrict__ B, float* __restrict__ C,
    int M, int N, int K, int lda, int ldb, int ldc,
    long sA, long sB, long sC,
    const float* __restrict__ res, long sRes,
    const float* __restrict__ alpha_ptr,
    const float* __restrict__ bias, long sBias, int act)
{
    __shared__ float As[16][64];
    __shared__ float Bs[16][64];
    const int z = blockIdx.z;
    A += (long)z * sA; B += (long)z * sB; C += (long)z * sC;
    if (res)  res  += (long)z * sRes;
    if (bias) bias += (long)z * sBias;
    const int bm0 = blockIdx.y * 64;
    const int bn0 = blockIdx.x * 64;
    const int tid = threadIdx.x;
    const int tx = tid & 15, ty = tid >> 4;
    const int lrow = tid >> 2, lseg = tid & 3;

    float acc[4][4] = {};
    for (int k0 = 0; k0 < K; k0 += 16) {
        float4 va = *reinterpret_cast<const float4*>(A + (long)(bm0 + lrow) * lda + k0 + lseg * 4);
        float4 vb = *reinterpret_cast<const float4*>(B + (long)(bn0 + lrow) * ldb + k0 + lseg * 4);
        As[lseg*4+0][lrow] = va.x; As[lseg*4+1][lrow] = va.y;
        As[lseg*4+2][lrow] = va.z; As[lseg*4+3][lrow] = va.w;
        Bs[lseg*4+0][lrow] = vb.x; Bs[lseg*4+1][lrow] = vb.y;
        Bs[lseg*4+2][lrow] = vb.z; Bs[lseg*4+3][lrow] = vb.w;
        __syncthreads();
        #pragma unroll
        for (int kk = 0; kk < 16; ++kk) {
            float4 af = *reinterpret_cast<const float4*>(&As[kk][ty*4]);
            float4 bf = *reinterpret_cast<const float4*>(&Bs[kk][tx*4]);
            float a[4] = {af.x, af.y, af.z, af.w};
            float b[4] = {bf.x, bf.y, bf.z, bf.w};
            #pragma unroll
            for (int i = 0; i < 4; ++i)
                #pragma unroll
                for (int j = 0; j < 4; ++j)
                    acc[i][j] += a[i] * b[j];
        }
        __syncthreads();
    }
    const float alpha = alpha_ptr ? alpha_ptr[0] : 1.0f;
    #pragma unroll
    for (int i = 0; i < 4; ++i) {
        const long rowoff = (long)(bm0 + ty*4 + i) * ldc + bn0 + tx*4;
        float vv[4];
        #pragma unroll
        for (int j = 0; j < 4; ++j) {
            float val = acc[i][j];
            if (bias) val += bias[bn0 + tx*4 + j];
            if (act == 1) val = (val > 20.f) ? val : log1pf(__expf(val));
            val *= alpha;
            vv[j] = val;
        }
        if (res) {
            float4 rv = *reinterpret_cast<const float4*>(res + rowoff);
            vv[0] += rv.x; vv[1] += rv.y; vv[2] += rv.z; vv[3] += rv.w;
        }
        float4 o; o.x = vv[0]; o.y = vv[1]; o.z = vv[2]; o.w = vv[3];
        *reinterpret_cast<float4*>(C + rowoff) = o;
    }
}

// ---------------- LayerNorm: one block per row of 512 ----------------
__global__ __launch_bounds__(256) void ln_kernel(const float* __restrict__ x, float* __restrict__ xn,
                                                 const float* __restrict__ nw, const float* __restrict__ nb)
{
    const int row = blockIdx.x;          // [3][4096]
    const int m = row >> 12;
    const int tid = threadIdx.x;
    const float2 v = *reinterpret_cast<const float2*>(x + (long)row * DMODEL + tid * 2);
    float s = v.x + v.y;
    float sq = v.x * v.x + v.y * v.y;
    #pragma unroll
    for (int off = 32; off > 0; off >>= 1) {
        s  += __shfl_down(s, off);
        sq += __shfl_down(sq, off);
    }
    __shared__ float ws_s[4], ws_q[4];
    const int wid = tid >> 6, lane = tid & 63;
    if (lane == 0) { ws_s[wid] = s; ws_q[wid] = sq; }
    __syncthreads();
    if (tid == 0) {
        float ts = ws_s[0] + ws_s[1] + ws_s[2] + ws_s[3];
        float tq = ws_q[0] + ws_q[1] + ws_q[2] + ws_q[3];
        float mu = ts / DMODEL;
        float var = tq / DMODEL - mu * mu;
        ws_s[0] = mu;
        ws_q[0] = rsqrtf(var + 1e-5f);
    }
    __syncthreads();
    const float mu = ws_s[0], rstd = ws_q[0];
    const int e0 = tid * 2;
    float2 w  = *reinterpret_cast<const float2*>(nw + m * DMODEL + e0);
    float2 bb = *reinterpret_cast<const float2*>(nb + m * DMODEL + e0);
    float2 o;
    o.x = (v.x - mu) * rstd * w.x + bb.x;
    o.y = (v.y - mu) * rstd * w.y + bb.y;
    *reinterpret_cast<float2*>(xn + (long)row * DMODEL + e0) = o;
}

// ---------------- depthwise causal conv(4) + SiLU ----------------
// in: xz_c [3][2][2048][1024]; out: xc same layout
__global__ __launch_bounds__(256) void conv_silu_kernel(const float* __restrict__ xz_c,
    const float* __restrict__ cw, const float* __restrict__ cb, float* __restrict__ xc)
{
    const long idx = (long)blockIdx.x * 256 + threadIdx.x;  // < 3*2*2048*1024
    const int c  = (int)(idx & 1023);
    const int l  = (int)((idx >> 10) & 2047);
    const int mb = (int)(idx >> 21);                        // m*2+b
    const int m  = mb >> 1;
    const float* xrow = xz_c + (long)mb * 2048 * 1024 + c;
    float acc = cb[m * DINNER + c];
    const float* w = cw + ((long)m * DINNER + c) * DCONV;
    #pragma unroll
    for (int k = 0; k < DCONV; ++k) {
        int lp = l - 3 + k;
        if (lp >= 0) acc += w[k] * xrow[(long)lp * 1024];
    }
    float sg = 1.f / (1.f + __expf(-acc));
    xc[idx] = acc * sg;
}

// ---------------- selective scan + skip + z-gating (in-place on delta buffer) ----------------
// one thread per (m,b,channel); h[16] in registers; B/C staged in LDS per 64-step chunk
__global__ __launch_bounds__(256) void scan_kernel(
    float* __restrict__ delta_io,          // [3][2][2048][1024]  in: delta, out: y*silu(z)
    const float* __restrict__ xc,          // [3][2][2048][1024]  u (post conv+silu)
    const float* __restrict__ dbc,         // [3][4096][64]   cols 32..47 = B, 48..63 = C
    const float* __restrict__ zbuf,        // [3][2][2048][1024]
    const float* __restrict__ A_log,       // [3][1024][16]
    const float* __restrict__ D_skip)      // [3][1024]
{
    const int bx = blockIdx.x;             // 0..23
    const int m  = bx >> 3;
    const int b  = (bx >> 2) & 1;
    const int cb = bx & 3;
    const int tid = threadIdx.x;
    const int c  = cb * 256 + tid;
    const int mb = m * 2 + b;

    float A[NSTATE];
    #pragma unroll
    for (int n = 0; n < NSTATE; ++n)
        A[n] = -__expf(A_log[((long)m * DINNER + c) * NSTATE + n]);
    const float Dsk = D_skip[m * DINNER + c];
    float h[NSTATE] = {};

    __shared__ float sBC[64][32];
    const float* dbc_mb = dbc + (long)m * MROWS * 64 + (long)b * LSEQ * 64;

    for (int t0 = 0; t0 < LSEQ; t0 += 64) {
        for (int i = tid; i < 64 * 32; i += 256) {
            int tt = i >> 5, j = i & 31;
            sBC[tt][j] = dbc_mb[(long)(t0 + tt) * 64 + 32 + j];
        }
        __syncthreads();
        for (int tt = 0; tt < 64; ++tt) {
            const long ridx = (long)mb * LSEQ + t0 + tt;
            const long idx  = ridx * DINNER + c;
            const float d = delta_io[idx];
            const float u = xc[idx];
            const float du = d * u;
            float y = 0.f;
            #pragma unroll
            for (int n = 0; n < NSTATE; ++n) {
                float e = __expf(d * A[n]);
                h[n] = e * h[n] + du * sBC[tt][n];
                y += h[n] * sBC[tt][16 + n];
            }
            y += u * Dsk;
            const float zv = zbuf[idx];
            const float sg = 1.f / (1.f + __expf(-zv));
            delta_io[idx] = y * (zv * sg);
        }
        __syncthreads();
    }
}

extern "C" void kernel_launch(void* const* d_in, const int* in_sizes, int n_in,
                              void* d_out, int out_size, void* d_ws, size_t ws_size,
                              hipStream_t stream)
{
    const float* v       = (const float*)d_in[0];
    const float* a       = (const float*)d_in[1];
    const float* t       = (const float*)d_in[2];
    const float* norm_w  = (const float*)d_in[3];
    const float* norm_b  = (const float*)d_in[4];
    const float* in_w    = (const float*)d_in[5];
    const float* conv_w  = (const float*)d_in[6];
    const float* conv_b  = (const float*)d_in[7];
    const float* xproj_w = (const float*)d_in[8];
    const float* dt_w    = (const float*)d_in[9];
    const float* dt_b    = (const float*)d_in[10];
    const float* A_log   = (const float*)d_in[11];
    const float* D_skip  = (const float*)d_in[12];
    const float* out_w   = (const float*)d_in[13];
    const float* couple_w= (const float*)d_in[14];
    const float* coef    = (const float*)d_in[15];
    float* out = (float*)d_out;

    // workspace layout (floats). total = 50,331,648 floats = 192 MiB
    float* ws    = (float*)d_ws;
    float* x_in  = ws;                     // [3][4096][512]
    float* xn    = x_in + 6291456;         // [3][4096][512]   (dead after in_proj)
    float* dbc   = xn;                     //   alias: [3][4096][64] written at step 5
    float* zbuf  = xn + 6291456;           // [3][4096][1024]
    float* xz_c  = zbuf + 12582912;        // [3][4096][1024]  (dead after conv)
    float* delta = xz_c;                   //   alias: [3][4096][1024] written at step 6
    float* xc    = xz_c + 12582912;        // [3][4096][1024]

    dim3 blk(256);

    // 1. cross-modal coupling: x_in[m] = prim[m] + coef[m] * sec[m] @ couple_w[m]^T
    const float* prim[3] = {v, a, t};
    const float* sec[3]  = {a, t, v};
    for (int mI = 0; mI < 3; ++mI) {
        gemm_nt_kernel<<<dim3(512/64, 4096/64, 1), blk, 0, stream>>>(
            sec[mI], couple_w + (long)mI*512*512, x_in + (long)mI*4096*512,
            4096, 512, 512, 512, 512, 512,
            0L, 0L, 0L,
            prim[mI], 0L, coef + mI, nullptr, 0L, 0);
    }
    // 2. layernorm
    ln_kernel<<<3*4096, 256, 0, stream>>>(x_in, xn, norm_w, norm_b);
    // 3a. in_proj, first half -> xz_c
    gemm_nt_kernel<<<dim3(1024/64, 64, 3), blk, 0, stream>>>(
        xn, in_w, xz_c, 4096, 1024, 512, 512, 512, 1024,
        2097152L, 1048576L, 4194304L, nullptr, 0L, nullptr, nullptr, 0L, 0);
    // 3b. in_proj, second half -> z
    gemm_nt_kernel<<<dim3(1024/64, 64, 3), blk, 0, stream>>>(
        xn, in_w + 1024*512, zbuf, 4096, 1024, 512, 512, 512, 1024,
        2097152L, 1048576L, 4194304L, nullptr, 0L, nullptr, nullptr, 0L, 0);
    // 4. depthwise causal conv + SiLU
    conv_silu_kernel<<<(3*2*2048*1024)/256, 256, 0, stream>>>(xz_c, conv_w, conv_b, xc);
    // 5. x_proj -> dbc [3][4096][64]
    gemm_nt_kernel<<<dim3(1, 64, 3), blk, 0, stream>>>(
        xc, xproj_w, dbc, 4096, 64, 1024, 1024, 1024, 64,
        4194304L, 65536L, 262144L, nullptr, 0L, nullptr, nullptr, 0L, 0);
    // 6. delta = softplus(dt @ dt_w^T + dt_b)   (dt = dbc cols 0..31, lda=64)
    gemm_nt_kernel<<<dim3(1024/64, 64, 3), blk, 0, stream>>>(
        dbc, dt_w, delta, 4096, 1024, 32, 64, 32, 1024,
        262144L, 32768L, 4194304L, nullptr, 0L, nullptr, dt_b, 1024L, 1);
    // 7. selective scan + skip + gating (in place on delta)
    scan_kernel<<<24, 256, 0, stream>>>(delta, xc, dbc, zbuf, A_log, D_skip);
    // 8. out_proj + residual -> d_out
    gemm_nt_kernel<<<dim3(512/64, 64, 3), blk, 0, stream>>>(
        delta, out_w, out, 4096, 512, 1024, 1024, 1024, 512,
        4194304L, 524288L, 2097152L, x_in, 2097152L, nullptr, nullptr, 0L, 0);
}

// Round 2
// 983.313 us; speedup vs baseline: 2.2372x; 2.2372x over previous
//
#include <hip/hip_runtime.h>
#include <hip/hip_bf16.h>

#define MODS 3
#define BSZ 2
#define LSEQ 2048
#define DMODEL 512
#define DINNER 1024
#define DTRANK 32
#define NSTATE 16
#define DCONV 4
#define MROWS (BSZ*LSEQ)   // 4096
#define NCHUNK 32
#define CHUNK 64           // LSEQ / NCHUNK

// ---------------- GEMM NT: C[z] = res[z] + alpha * act(A[z] @ B[z]^T + bias[z]) ----------------
__global__ __launch_bounds__(256) void gemm_nt_kernel(
    const float* __restrict__ A, const float* __restrict__ B, float* __restrict__ C,
    int M, int N, int K, int lda, int ldb, int ldc,
    long sA, long sB, long sC,
    const float* __restrict__ res, long sRes,
    const float* __restrict__ alpha_ptr,
    const float* __restrict__ bias, long sBias, int act)
{
    __shared__ float As[16][64];
    __shared__ float Bs[16][64];
    const int z = blockIdx.z;
    A += (long)z * sA; B += (long)z * sB; C += (long)z * sC;
    if (res)  res  += (long)z * sRes;
    if (bias) bias += (long)z * sBias;
    const int bm0 = blockIdx.y * 64;
    const int bn0 = blockIdx.x * 64;
    const int tid = threadIdx.x;
    const int tx = tid & 15, ty = tid >> 4;
    const int lrow = tid >> 2, lseg = tid & 3;

    float acc[4][4] = {};
    for (int k0 = 0; k0 < K; k0 += 16) {
        float4 va = *reinterpret_cast<const float4*>(A + (long)(bm0 + lrow) * lda + k0 + lseg * 4);
        float4 vb = *reinterpret_cast<const float4*>(B + (long)(bn0 + lrow) * ldb + k0 + lseg * 4);
        As[lseg*4+0][lrow] = va.x; As[lseg*4+1][lrow] = va.y;
        As[lseg*4+2][lrow] = va.z; As[lseg*4+3][lrow] = va.w;
        Bs[lseg*4+0][lrow] = vb.x; Bs[lseg*4+1][lrow] = vb.y;
        Bs[lseg*4+2][lrow] = vb.z; Bs[lseg*4+3][lrow] = vb.w;
        __syncthreads();
        #pragma unroll
        for (int kk = 0; kk < 16; ++kk) {
            float4 af = *reinterpret_cast<const float4*>(&As[kk][ty*4]);
            float4 bf = *reinterpret_cast<const float4*>(&Bs[kk][tx*4]);
            float a[4] = {af.x, af.y, af.z, af.w};
            float b[4] = {bf.x, bf.y, bf.z, bf.w};
            #pragma unroll
            for (int i = 0; i < 4; ++i)
                #pragma unroll
                for (int j = 0; j < 4; ++j)
                    acc[i][j] += a[i] * b[j];
        }
        __syncthreads();
    }
    const float alpha = alpha_ptr ? alpha_ptr[0] : 1.0f;
    #pragma unroll
    for (int i = 0; i < 4; ++i) {
        const long rowoff = (long)(bm0 + ty*4 + i) * ldc + bn0 + tx*4;
        float vv[4];
        #pragma unroll
        for (int j = 0; j < 4; ++j) {
            float val = acc[i][j];
            if (bias) val += bias[bn0 + tx*4 + j];
            if (act == 1) val = (val > 20.f) ? val : log1pf(__expf(val));
            val *= alpha;
            vv[j] = val;
        }
        if (res) {
            float4 rv = *reinterpret_cast<const float4*>(res + rowoff);
            vv[0] += rv.x; vv[1] += rv.y; vv[2] += rv.z; vv[3] += rv.w;
        }
        float4 o; o.x = vv[0]; o.y = vv[1]; o.z = vv[2]; o.w = vv[3];
        *reinterpret_cast<float4*>(C + rowoff) = o;
    }
}

// ---------------- LayerNorm ----------------
__global__ __launch_bounds__(256) void ln_kernel(const float* __restrict__ x, float* __restrict__ xn,
                                                 const float* __restrict__ nw, const float* __restrict__ nb)
{
    const int row = blockIdx.x;
    const int m = row >> 12;
    const int tid = threadIdx.x;
    const float2 v = *reinterpret_cast<const float2*>(x + (long)row * DMODEL + tid * 2);
    float s = v.x + v.y;
    float sq = v.x * v.x + v.y * v.y;
    #pragma unroll
    for (int off = 32; off > 0; off >>= 1) {
        s  += __shfl_down(s, off);
        sq += __shfl_down(sq, off);
    }
    __shared__ float ws_s[4], ws_q[4];
    const int wid = tid >> 6, lane = tid & 63;
    if (lane == 0) { ws_s[wid] = s; ws_q[wid] = sq; }
    __syncthreads();
    if (tid == 0) {
        float ts = ws_s[0] + ws_s[1] + ws_s[2] + ws_s[3];
        float tq = ws_q[0] + ws_q[1] + ws_q[2] + ws_q[3];
        float mu = ts / DMODEL;
        float var = tq / DMODEL - mu * mu;
        ws_s[0] = mu;
        ws_q[0] = rsqrtf(var + 1e-5f);
    }
    __syncthreads();
    const float mu = ws_s[0], rstd = ws_q[0];
    const int e0 = tid * 2;
    float2 w  = *reinterpret_cast<const float2*>(nw + m * DMODEL + e0);
    float2 bb = *reinterpret_cast<const float2*>(nb + m * DMODEL + e0);
    float2 o;
    o.x = (v.x - mu) * rstd * w.x + bb.x;
    o.y = (v.y - mu) * rstd * w.y + bb.y;
    *reinterpret_cast<float2*>(xn + (long)row * DMODEL + e0) = o;
}

// ---------------- depthwise causal conv(4) + SiLU ----------------
__global__ __launch_bounds__(256) void conv_silu_kernel(const float* __restrict__ xz_c,
    const float* __restrict__ cw, const float* __restrict__ cb, float* __restrict__ xc)
{
    const long idx = (long)blockIdx.x * 256 + threadIdx.x;
    const int c  = (int)(idx & 1023);
    const int l  = (int)((idx >> 10) & 2047);
    const int mb = (int)(idx >> 21);
    const int m  = mb >> 1;
    const float* xrow = xz_c + (long)mb * 2048 * 1024 + c;
    float acc = cb[m * DINNER + c];
    const float* w = cw + ((long)m * DINNER + c) * DCONV;
    #pragma unroll
    for (int k = 0; k < DCONV; ++k) {
        int lp = l - 3 + k;
        if (lp >= 0) acc += w[k] * xrow[(long)lp * 1024];
    }
    float sg = 1.f / (1.f + __expf(-acc));
    xc[idx] = acc * sg;
}

// ---------------- chunk-parallel selective scan ----------------
// Pass 1: per (mb, cgroup, chunk): local scan with h=0 -> final state F[16], decay prod P[16]
__global__ __launch_bounds__(256) void scan_pass1_kernel(
    const float* __restrict__ delta, const float* __restrict__ xc,
    const float* __restrict__ dbc, const float* __restrict__ A_log,
    float* __restrict__ Fbuf, float* __restrict__ Dbuf)
{
    const int bx = blockIdx.x;             // mb(6) x cg(4) x chunk(32)
    const int chunk = bx & (NCHUNK - 1);
    const int cg = (bx >> 5) & 3;
    const int mb = bx >> 7;
    const int m = mb >> 1, b = mb & 1;
    const int tid = threadIdx.x;
    const int c = cg * 256 + tid;

    float A[NSTATE];
    #pragma unroll
    for (int n = 0; n < NSTATE; ++n)
        A[n] = -__expf(A_log[((long)m * DINNER + c) * NSTATE + n]);
    float h[NSTATE] = {};
    float P[NSTATE];
    #pragma unroll
    for (int n = 0; n < NSTATE; ++n) P[n] = 1.f;

    __shared__ float sB[CHUNK][NSTATE];
    const float* dbc_mb = dbc + (long)m * MROWS * 64 + (long)b * LSEQ * 64;
    const int t0 = chunk * CHUNK;
    for (int i = tid; i < CHUNK * NSTATE; i += 256) {
        int tt = i >> 4, j = i & 15;
        sB[tt][j] = dbc_mb[(long)(t0 + tt) * 64 + 32 + j];
    }
    __syncthreads();

    const long base = ((long)mb * LSEQ + t0) * DINNER + c;
    #pragma unroll 4
    for (int tt = 0; tt < CHUNK; ++tt) {
        const float d = delta[base + (long)tt * DINNER];
        const float u = xc[base + (long)tt * DINNER];
        const float du = d * u;
        #pragma unroll
        for (int n = 0; n < NSTATE; ++n) {
            float e = __expf(d * A[n]);
            h[n] = e * h[n] + du * sB[tt][n];
            P[n] *= e;
        }
    }
    const long o = (((long)mb * NCHUNK + chunk) * DINNER + c) * NSTATE;
    #pragma unroll
    for (int n = 0; n < NSTATE; ++n) { Fbuf[o + n] = h[n]; Dbuf[o + n] = P[n]; }
}

// Pass 2: per (mb, c, n): sequential combine over chunks; writes h_in per chunk in-place into F
__global__ __launch_bounds__(256) void scan_pass2_kernel(float* __restrict__ Fbuf,
                                                         const float* __restrict__ Dbuf)
{
    const long idx = (long)blockIdx.x * 256 + threadIdx.x;  // < 6*1024*16
    const int mb = (int)(idx >> 14);
    const int cn = (int)(idx & 16383);
    float run = 0.f;
    for (int k = 0; k < NCHUNK; ++k) {
        const long o = ((long)mb * NCHUNK + k) * 16384 + cn;
        const float f = Fbuf[o];
        const float p = Dbuf[o];
        Fbuf[o] = run;
        run = p * run + f;
    }
}

// Pass 3: local scan with correct h_in; fused D-skip + z-gating; writes into delta buffer
__global__ __launch_bounds__(256) void scan_pass3_kernel(
    float* __restrict__ delta_io, const float* __restrict__ xc,
    const float* __restrict__ dbc, const float* __restrict__ zbuf,
    const float* __restrict__ A_log, const float* __restrict__ D_skip,
    const float* __restrict__ Hin)
{
    const int bx = blockIdx.x;
    const int chunk = bx & (NCHUNK - 1);
    const int cg = (bx >> 5) & 3;
    const int mb = bx >> 7;
    const int m = mb >> 1, b = mb & 1;
    const int tid = threadIdx.x;
    const int c = cg * 256 + tid;

    float A[NSTATE];
    #pragma unroll
    for (int n = 0; n < NSTATE; ++n)
        A[n] = -__expf(A_log[((long)m * DINNER + c) * NSTATE + n]);
    const float Dsk = D_skip[m * DINNER + c];

    float h[NSTATE];
    const long ho = (((long)mb * NCHUNK + chunk) * DINNER + c) * NSTATE;
    #pragma unroll
    for (int n = 0; n < NSTATE; ++n) h[n] = Hin[ho + n];

    __shared__ float sBC[CHUNK][2 * NSTATE];
    const float* dbc_mb = dbc + (long)m * MROWS * 64 + (long)b * LSEQ * 64;
    const int t0 = chunk * CHUNK;
    for (int i = tid; i < CHUNK * 2 * NSTATE; i += 256) {
        int tt = i >> 5, j = i & 31;
        sBC[tt][j] = dbc_mb[(long)(t0 + tt) * 64 + 32 + j];
    }
    __syncthreads();

    const long base = ((long)mb * LSEQ + t0) * DINNER + c;
    #pragma unroll 4
    for (int tt = 0; tt < CHUNK; ++tt) {
        const long idx = base + (long)tt * DINNER;
        const float d = delta_io[idx];
        const float u = xc[idx];
        const float zv = zbuf[idx];
        const float du = d * u;
        float y = 0.f;
        #pragma unroll
        for (int n = 0; n < NSTATE; ++n) {
            float e = __expf(d * A[n]);
            h[n] = e * h[n] + du * sBC[tt][n];
            y += h[n] * sBC[tt][16 + n];
        }
        y += u * Dsk;
        const float sg = 1.f / (1.f + __expf(-zv));
        delta_io[idx] = y * (zv * sg);
    }
}

extern "C" void kernel_launch(void* const* d_in, const int* in_sizes, int n_in,
                              void* d_out, int out_size, void* d_ws, size_t ws_size,
                              hipStream_t stream)
{
    const float* v       = (const float*)d_in[0];
    const float* a       = (const float*)d_in[1];
    const float* t       = (const float*)d_in[2];
    const float* norm_w  = (const float*)d_in[3];
    const float* norm_b  = (const float*)d_in[4];
    const float* in_w    = (const float*)d_in[5];
    const float* conv_w  = (const float*)d_in[6];
    const float* conv_b  = (const float*)d_in[7];
    const float* xproj_w = (const float*)d_in[8];
    const float* dt_w    = (const float*)d_in[9];
    const float* dt_b    = (const float*)d_in[10];
    const float* A_log   = (const float*)d_in[11];
    const float* D_skip  = (const float*)d_in[12];
    const float* out_w   = (const float*)d_in[13];
    const float* couple_w= (const float*)d_in[14];
    const float* coef    = (const float*)d_in[15];
    float* out = (float*)d_out;

    // workspace layout (floats). total = 50,331,648 floats = 192 MiB
    float* ws    = (float*)d_ws;
    float* x_in  = ws;                     // [3][4096][512]
    float* xn    = x_in + 6291456;         // [3][4096][512]   (dead after in_proj)
    float* dbc   = xn;                     //   alias: [3][4096][64] written at step 5
    float* zbuf  = xn + 6291456;           // [3][4096][1024]
    float* xz_c  = zbuf + 12582912;        // [3][4096][1024]  (dead after conv)
    float* delta = xz_c;                   //   alias: [3][4096][1024] written at step 6
    float* xc    = xz_c + 12582912;        // [3][4096][1024]

    // chunk-scan scratch lives in d_out (6.29M floats; fully rewritten by step 8)
    float* Fbuf = out;                     // [6][32][1024][16] = 3,145,728 floats
    float* Dbuf = out + 3145728;           // [6][32][1024][16]

    dim3 blk(256);

    // 1. cross-modal coupling
    const float* prim[3] = {v, a, t};
    const float* sec[3]  = {a, t, v};
    for (int mI = 0; mI < 3; ++mI) {
        gemm_nt_kernel<<<dim3(512/64, 4096/64, 1), blk, 0, stream>>>(
            sec[mI], couple_w + (long)mI*512*512, x_in + (long)mI*4096*512,
            4096, 512, 512, 512, 512, 512,
            0L, 0L, 0L,
            prim[mI], 0L, coef + mI, nullptr, 0L, 0);
    }
    // 2. layernorm
    ln_kernel<<<3*4096, 256, 0, stream>>>(x_in, xn, norm_w, norm_b);
    // 3a/3b. in_proj halves
    gemm_nt_kernel<<<dim3(1024/64, 64, 3), blk, 0, stream>>>(
        xn, in_w, xz_c, 4096, 1024, 512, 512, 512, 1024,
        2097152L, 1048576L, 4194304L, nullptr, 0L, nullptr, nullptr, 0L, 0);
    gemm_nt_kernel<<<dim3(1024/64, 64, 3), blk, 0, stream>>>(
        xn, in_w + 1024*512, zbuf, 4096, 1024, 512, 512, 512, 1024,
        2097152L, 1048576L, 4194304L, nullptr, 0L, nullptr, nullptr, 0L, 0);
    // 4. conv + SiLU
    conv_silu_kernel<<<(3*2*2048*1024)/256, 256, 0, stream>>>(xz_c, conv_w, conv_b, xc);
    // 5. x_proj -> dbc
    gemm_nt_kernel<<<dim3(1, 64, 3), blk, 0, stream>>>(
        xc, xproj_w, dbc, 4096, 64, 1024, 1024, 1024, 64,
        4194304L, 65536L, 262144L, nullptr, 0L, nullptr, nullptr, 0L, 0);
    // 6. delta = softplus(dt @ dt_w^T + dt_b)
    gemm_nt_kernel<<<dim3(1024/64, 64, 3), blk, 0, stream>>>(
        dbc, dt_w, delta, 4096, 1024, 32, 64, 32, 1024,
        262144L, 32768L, 4194304L, nullptr, 0L, nullptr, dt_b, 1024L, 1);
    // 7. chunk-parallel scan
    scan_pass1_kernel<<<6*4*NCHUNK, 256, 0, stream>>>(delta, xc, dbc, A_log, Fbuf, Dbuf);
    scan_pass2_kernel<<<(6*1024*16)/256, 256, 0, stream>>>(Fbuf, Dbuf);
    scan_pass3_kernel<<<6*4*NCHUNK, 256, 0, stream>>>(delta, xc, dbc, zbuf, A_log, D_skip, Fbuf);
    // 8. out_proj + residual -> d_out
    gemm_nt_kernel<<<dim3(512/64, 64, 3), blk, 0, stream>>>(
        delta, out_w, out, 4096, 512, 1024, 1024, 1024, 512,
        4194304L, 524288L, 2097152L, x_in, 2097152L, nullptr, nullptr, 0L, 0);
}

// Round 3
// 486.302 us; speedup vs baseline: 4.5236x; 2.0220x over previous
//
#include <hip/hip_runtime.h>
#include <hip/hip_bf16.h>

#define MODS 3
#define BSZ 2
#define LSEQ 2048
#define DMODEL 512
#define DINNER 1024
#define DTRANK 32
#define NSTATE 16
#define DCONV 4
#define MROWS (BSZ*LSEQ)   // 4096
#define NCHUNK 32
#define CHUNK 64           // LSEQ / NCHUNK

typedef __attribute__((ext_vector_type(8))) short short8v;
typedef __attribute__((ext_vector_type(4))) short short4v;
typedef __attribute__((ext_vector_type(2))) short short2v;
typedef __attribute__((ext_vector_type(4))) float f32x4;

__device__ __forceinline__ short f2bf(float x) {
    __hip_bfloat16 h = __float2bfloat16(x);
    return __builtin_bit_cast(short, h);
}
__device__ __forceinline__ float bf2f(short s) {
    return __uint_as_float(((unsigned)(unsigned short)s) << 16);
}
__device__ __forceinline__ void gl_lds16(const short* g, short* l) {
    __builtin_amdgcn_global_load_lds(
        (const __attribute__((address_space(1))) unsigned int*)g,
        (__attribute__((address_space(3))) unsigned int*)l, 16, 0, 0);
}

// ---------------- bf16 MFMA GEMM NT ----------------
// C[z] = res[z] + coef[z] * act(A[z] @ B[z]^T + bias[z])
// A: [M,K] bf16, B: [N,K] bf16 (NT). Tile 128 x (NJ*32). M mult of 128, K mult of 32.
template<int NJ>
__global__ __launch_bounds__(256) void gemm_bf16(
    const __hip_bfloat16* __restrict__ A_, const __hip_bfloat16* __restrict__ B_,
    int K, int lda, int ldb, long sA, long sB,
    float* __restrict__ Cf, __hip_bfloat16* __restrict__ Cb, int ldc, long sC,
    const float* __restrict__ res, long sRes,
    const float* __restrict__ coef_base, int coef_stride,
    const float* __restrict__ bias, long sBias, int act)
{
    constexpr int BN = NJ * 32;
    __shared__ alignas(16) short As[128 * 32];
    __shared__ alignas(16) short Bs[BN * 32];
    const int z = blockIdx.z;
    const int bm0 = blockIdx.y * 128;
    const int bn0 = blockIdx.x * BN;
    const short* Ag = (const short*)A_ + z * sA + (long)bm0 * lda;
    const short* Bg = (const short*)B_ + z * sB + (long)bn0 * ldb;
    const int tid = threadIdx.x;
    const int lane = tid & 63;
    const int w = tid >> 6;
    const int wr = w >> 1, wc = w & 1;
    const int lr = lane & 15, lk = (lane >> 4) * 8;
    const int arow = tid >> 2;          // 0..63
    const int aseg = (tid & 3) * 8;     // 0,8,16,24 (elements)

    f32x4 acc[4][NJ];
    #pragma unroll
    for (int i = 0; i < 4; ++i)
        #pragma unroll
        for (int j = 0; j < NJ; ++j)
            acc[i][j] = (f32x4){0.f, 0.f, 0.f, 0.f};

    for (int k0 = 0; k0 < K; k0 += 32) {
        gl_lds16(Ag + (long)arow * lda + k0 + aseg, As + tid * 8);
        gl_lds16(Ag + (long)(64 + arow) * lda + k0 + aseg, As + 2048 + tid * 8);
        gl_lds16(Bg + (long)arow * ldb + k0 + aseg, Bs + tid * 8);
        if constexpr (NJ == 4)
            gl_lds16(Bg + (long)(64 + arow) * ldb + k0 + aseg, Bs + 2048 + tid * 8);
        __syncthreads();
        short8v af[4], bfr[NJ];
        #pragma unroll
        for (int i = 0; i < 4; ++i)
            af[i] = *(const short8v*)&As[(wr * 64 + i * 16 + lr) * 32 + lk];
        #pragma unroll
        for (int j = 0; j < NJ; ++j)
            bfr[j] = *(const short8v*)&Bs[(wc * NJ * 16 + j * 16 + lr) * 32 + lk];
        #pragma unroll
        for (int i = 0; i < 4; ++i)
            #pragma unroll
            for (int j = 0; j < NJ; ++j)
                acc[i][j] = __builtin_amdgcn_mfma_f32_16x16x32_bf16(af[i], bfr[j], acc[i][j], 0, 0, 0);
        __syncthreads();
    }

    const float alpha = coef_base ? coef_base[z * coef_stride] : 1.0f;
    const float* resz = res ? res + z * sRes : nullptr;
    const float* biasz = bias ? bias + z * sBias : nullptr;
    float* Cfz = Cf ? Cf + z * sC : nullptr;
    __hip_bfloat16* Cbz = Cb ? Cb + z * sC : nullptr;
    #pragma unroll
    for (int i = 0; i < 4; ++i) {
        #pragma unroll
        for (int r = 0; r < 4; ++r) {
            const int row = bm0 + wr * 64 + i * 16 + (lane >> 4) * 4 + r;
            #pragma unroll
            for (int j = 0; j < NJ; ++j) {
                const int col = bn0 + wc * NJ * 16 + j * 16 + lr;
                float val = acc[i][j][r];
                if (biasz) val += biasz[col];
                if (act == 1) val = (val > 20.f) ? val : log1pf(__expf(val));
                val *= alpha;
                if (resz) val += resz[(long)row * ldc + col];
                if (Cfz) Cfz[(long)row * ldc + col] = val;
                else     Cbz[(long)row * ldc + col] = __float2bfloat16(val);
            }
        }
    }
}

// ---------------- stack: x_in = [v;a;t] f32, sec_bf = [a;t;v] bf16 ----------------
__global__ __launch_bounds__(256) void stack_vat_kernel(
    const float* __restrict__ v, const float* __restrict__ a, const float* __restrict__ t,
    float* __restrict__ x_in, __hip_bfloat16* __restrict__ sec_bf)
{
    const long idx = (long)blockIdx.x * 256 + threadIdx.x;   // < 3 * 524288
    const int m = (int)(idx >> 19);
    const long off = idx & 524287;
    const float* prim = (m == 0) ? v : (m == 1) ? a : t;
    const float* sec  = (m == 0) ? a : (m == 1) ? t : v;
    float4 pv = ((const float4*)prim)[off];
    float4 sv = ((const float4*)sec)[off];
    ((float4*)x_in)[idx] = pv;
    short4v s;
    s.x = f2bf(sv.x); s.y = f2bf(sv.y); s.z = f2bf(sv.z); s.w = f2bf(sv.w);
    ((short4v*)sec_bf)[idx] = s;
}

// ---------------- generic f32 -> bf16 ----------------
__global__ __launch_bounds__(256) void cvt_bf16_kernel(const float* __restrict__ in,
                                                       __hip_bfloat16* __restrict__ outp, int n4)
{
    const int idx = blockIdx.x * 256 + threadIdx.x;
    if (idx < n4) {
        float4 vv = ((const float4*)in)[idx];
        short4v s;
        s.x = f2bf(vv.x); s.y = f2bf(vv.y); s.z = f2bf(vv.z); s.w = f2bf(vv.w);
        ((short4v*)outp)[idx] = s;
    }
}

// ---------------- LayerNorm: f32 in -> bf16 out ----------------
__global__ __launch_bounds__(256) void ln_kernel(const float* __restrict__ x, __hip_bfloat16* __restrict__ xn,
                                                 const float* __restrict__ nw, const float* __restrict__ nb)
{
    const int row = blockIdx.x;          // [3][4096]
    const int m = row >> 12;
    const int tid = threadIdx.x;
    const float2 v = *reinterpret_cast<const float2*>(x + (long)row * DMODEL + tid * 2);
    float s = v.x + v.y;
    float sq = v.x * v.x + v.y * v.y;
    #pragma unroll
    for (int off = 32; off > 0; off >>= 1) {
        s  += __shfl_down(s, off);
        sq += __shfl_down(sq, off);
    }
    __shared__ float ws_s[4], ws_q[4];
    const int wid = tid >> 6, lane = tid & 63;
    if (lane == 0) { ws_s[wid] = s; ws_q[wid] = sq; }
    __syncthreads();
    if (tid == 0) {
        float ts = ws_s[0] + ws_s[1] + ws_s[2] + ws_s[3];
        float tq = ws_q[0] + ws_q[1] + ws_q[2] + ws_q[3];
        float mu = ts / DMODEL;
        float var = tq / DMODEL - mu * mu;
        ws_s[0] = mu;
        ws_q[0] = rsqrtf(var + 1e-5f);
    }
    __syncthreads();
    const float mu = ws_s[0], rstd = ws_q[0];
    const int e0 = tid * 2;
    float2 w  = *reinterpret_cast<const float2*>(nw + m * DMODEL + e0);
    float2 bb = *reinterpret_cast<const float2*>(nb + m * DMODEL + e0);
    short2v o;
    o.x = f2bf((v.x - mu) * rstd * w.x + bb.x);
    o.y = f2bf((v.y - mu) * rstd * w.y + bb.y);
    *reinterpret_cast<short2v*>((short*)xn + (long)row * DMODEL + e0) = o;
}

// ---------------- depthwise causal conv(4) + SiLU, 8 channels/thread, bf16 ----------------
__global__ __launch_bounds__(256) void conv_silu_kernel(const __hip_bfloat16* __restrict__ xin,
    const float* __restrict__ cw, const float* __restrict__ cb, __hip_bfloat16* __restrict__ xc)
{
    const long idx = (long)blockIdx.x * 256 + threadIdx.x;  // < 3*2*2048*128
    const int c8 = (int)(idx & 127);
    const int l  = (int)((idx >> 7) & 2047);
    const int mb = (int)(idx >> 18);
    const int m  = mb >> 1;
    const int c0 = c8 * 8;
    float acc[8];
    #pragma unroll
    for (int j = 0; j < 8; ++j) acc[j] = cb[m * DINNER + c0 + j];
    const short* base = (const short*)xin + ((long)mb * LSEQ) * DINNER + c0;
    #pragma unroll
    for (int k = 0; k < DCONV; ++k) {
        const int lp = l - 3 + k;
        if (lp >= 0) {
            short8v vv = *(const short8v*)(base + (long)lp * DINNER);
            #pragma unroll
            for (int j = 0; j < 8; ++j) {
                const float wv = cw[((long)m * DINNER + c0 + j) * DCONV + k];
                acc[j] += wv * bf2f(vv[j]);
            }
        }
    }
    short8v o;
    #pragma unroll
    for (int j = 0; j < 8; ++j) {
        const float sg = 1.f / (1.f + __expf(-acc[j]));
        o[j] = f2bf(acc[j] * sg);
    }
    *(short8v*)((short*)xc + ((long)mb * LSEQ + l) * DINNER + c0) = o;
}

// ---------------- chunk-parallel selective scan (bf16 activations) ----------------
__global__ __launch_bounds__(256) void scan_pass1_kernel(
    const __hip_bfloat16* __restrict__ delta, const __hip_bfloat16* __restrict__ xc,
    const __hip_bfloat16* __restrict__ dbc, const float* __restrict__ A_log,
    float* __restrict__ Fbuf, float* __restrict__ Dbuf)
{
    const int bx = blockIdx.x;             // mb(6) x cg(4) x chunk(32)
    const int chunk = bx & (NCHUNK - 1);
    const int cg = (bx >> 5) & 3;
    const int mb = bx >> 7;
    const int m = mb >> 1, b = mb & 1;
    const int tid = threadIdx.x;
    const int c = cg * 256 + tid;

    float A[NSTATE];
    #pragma unroll
    for (int n = 0; n < NSTATE; ++n)
        A[n] = -__expf(A_log[((long)m * DINNER + c) * NSTATE + n]);
    float h[NSTATE] = {};
    float P[NSTATE];
    #pragma unroll
    for (int n = 0; n < NSTATE; ++n) P[n] = 1.f;

    __shared__ float sB[CHUNK][NSTATE];
    const short* dbc_mb = (const short*)dbc + (long)m * MROWS * 64 + (long)b * LSEQ * 64;
    const int t0 = chunk * CHUNK;
    for (int i = tid; i < CHUNK * NSTATE; i += 256) {
        int tt = i >> 4, j = i & 15;
        sB[tt][j] = bf2f(dbc_mb[(long)(t0 + tt) * 64 + 32 + j]);
    }
    __syncthreads();

    const short* dp = (const short*)delta;
    const short* up = (const short*)xc;
    const long base = ((long)mb * LSEQ + t0) * DINNER + c;
    #pragma unroll 4
    for (int tt = 0; tt < CHUNK; ++tt) {
        const float d = bf2f(dp[base + (long)tt * DINNER]);
        const float u = bf2f(up[base + (long)tt * DINNER]);
        const float du = d * u;
        #pragma unroll
        for (int n = 0; n < NSTATE; ++n) {
            float e = __expf(d * A[n]);
            h[n] = e * h[n] + du * sB[tt][n];
            P[n] *= e;
        }
    }
    const long o = (((long)mb * NCHUNK + chunk) * DINNER + c) * NSTATE;
    #pragma unroll
    for (int n = 0; n < NSTATE; ++n) { Fbuf[o + n] = h[n]; Dbuf[o + n] = P[n]; }
}

__global__ __launch_bounds__(256) void scan_pass2_kernel(float* __restrict__ Fbuf,
                                                         const float* __restrict__ Dbuf)
{
    const long idx = (long)blockIdx.x * 256 + threadIdx.x;  // < 6*1024*16
    const int mb = (int)(idx >> 14);
    const int cn = (int)(idx & 16383);
    float run = 0.f;
    for (int k = 0; k < NCHUNK; ++k) {
        const long o = ((long)mb * NCHUNK + k) * 16384 + cn;
        const float f = Fbuf[o];
        const float p = Dbuf[o];
        Fbuf[o] = run;
        run = p * run + f;
    }
}

__global__ __launch_bounds__(256) void scan_pass3_kernel(
    const __hip_bfloat16* __restrict__ delta, const __hip_bfloat16* __restrict__ xc,
    const __hip_bfloat16* __restrict__ dbc, const __hip_bfloat16* __restrict__ zbuf,
    const float* __restrict__ A_log, const float* __restrict__ D_skip,
    const float* __restrict__ Hin, __hip_bfloat16* __restrict__ ybuf)
{
    const int bx = blockIdx.x;
    const int chunk = bx & (NCHUNK - 1);
    const int cg = (bx >> 5) & 3;
    const int mb = bx >> 7;
    const int m = mb >> 1, b = mb & 1;
    const int tid = threadIdx.x;
    const int c = cg * 256 + tid;

    float A[NSTATE];
    #pragma unroll
    for (int n = 0; n < NSTATE; ++n)
        A[n] = -__expf(A_log[((long)m * DINNER + c) * NSTATE + n]);
    const float Dsk = D_skip[m * DINNER + c];

    float h[NSTATE];
    const long ho = (((long)mb * NCHUNK + chunk) * DINNER + c) * NSTATE;
    #pragma unroll
    for (int n = 0; n < NSTATE; ++n) h[n] = Hin[ho + n];

    __shared__ float sBC[CHUNK][2 * NSTATE];
    const short* dbc_mb = (const short*)dbc + (long)m * MROWS * 64 + (long)b * LSEQ * 64;
    const int t0 = chunk * CHUNK;
    for (int i = tid; i < CHUNK * 2 * NSTATE; i += 256) {
        int tt = i >> 5, j = i & 31;
        sBC[tt][j] = bf2f(dbc_mb[(long)(t0 + tt) * 64 + 32 + j]);
    }
    __syncthreads();

    const short* dp = (const short*)delta;
    const short* up = (const short*)xc;
    const short* zp = (const short*)zbuf;
    short* yp = (short*)ybuf;
    const long base = ((long)mb * LSEQ + t0) * DINNER + c;
    #pragma unroll 4
    for (int tt = 0; tt < CHUNK; ++tt) {
        const long idx = base + (long)tt * DINNER;
        const float d = bf2f(dp[idx]);
        const float u = bf2f(up[idx]);
        const float zv = bf2f(zp[idx]);
        const float du = d * u;
        float y = 0.f;
        #pragma unroll
        for (int n = 0; n < NSTATE; ++n) {
            float e = __expf(d * A[n]);
            h[n] = e * h[n] + du * sBC[tt][n];
            y += h[n] * sBC[tt][16 + n];
        }
        y += u * Dsk;
        const float sg = 1.f / (1.f + __expf(-zv));
        yp[idx] = f2bf(y * (zv * sg));
    }
}

extern "C" void kernel_launch(void* const* d_in, const int* in_sizes, int n_in,
                              void* d_out, int out_size, void* d_ws, size_t ws_size,
                              hipStream_t stream)
{
    const float* v       = (const float*)d_in[0];
    const float* a       = (const float*)d_in[1];
    const float* t       = (const float*)d_in[2];
    const float* norm_w  = (const float*)d_in[3];
    const float* norm_b  = (const float*)d_in[4];
    const float* in_w    = (const float*)d_in[5];
    const float* conv_w  = (const float*)d_in[6];
    const float* conv_b  = (const float*)d_in[7];
    const float* xproj_w = (const float*)d_in[8];
    const float* dt_w    = (const float*)d_in[9];
    const float* dt_b    = (const float*)d_in[10];
    const float* A_log   = (const float*)d_in[11];
    const float* D_skip  = (const float*)d_in[12];
    const float* out_w   = (const float*)d_in[13];
    const float* couple_w= (const float*)d_in[14];
    const float* coef    = (const float*)d_in[15];
    float* out = (float*)d_out;

    typedef __hip_bfloat16 bf;
    float* x_in   = (float*)d_ws;                       // [3][4096][512] f32
    bf* xn_bf     = (bf*)(x_in + 6291456);              // [3][4096][512]
    bf* sec_bf    = xn_bf + 6291456;                    // [3][4096][512]
    bf* xcpre_bf  = sec_bf + 6291456;                   // [3][4096][1024]  (later reused as ybuf)
    bf* z_bf      = xcpre_bf + 12582912;                // [3][4096][1024]
    bf* xc_bf     = z_bf + 12582912;                    // [3][4096][1024]
    bf* delta_bf  = xc_bf + 12582912;                   // [3][4096][1024]
    bf* dbc_bf    = delta_bf + 12582912;                // [3][4096][64]
    bf* cw_bf     = dbc_bf + 786432;                    // [3][512][512]
    bf* inw_bf    = cw_bf + 786432;                     // [3][2048][512]
    bf* xpw_bf    = inw_bf + 3145728;                   // [3][64][1024]
    bf* dtw_bf    = xpw_bf + 196608;                    // [3][1024][32]
    bf* outw_bf   = dtw_bf + 98304;                     // [3][512][1024]
    bf* ybuf_bf   = xcpre_bf;                           // alias (xcpre dead after conv)

    float* Fbuf = out;                                  // [6][32][1024][16] in d_out
    float* Dbuf = out + 3145728;

    dim3 blk(256);

    // 0. conversions
    stack_vat_kernel<<<6144, blk, 0, stream>>>(v, a, t, x_in, sec_bf);
    cvt_bf16_kernel<<<768,  blk, 0, stream>>>(couple_w, cw_bf,  196608);
    cvt_bf16_kernel<<<3072, blk, 0, stream>>>(in_w,     inw_bf, 786432);
    cvt_bf16_kernel<<<192,  blk, 0, stream>>>(xproj_w,  xpw_bf, 49152);
    cvt_bf16_kernel<<<96,   blk, 0, stream>>>(dt_w,     dtw_bf, 24576);
    cvt_bf16_kernel<<<1536, blk, 0, stream>>>(out_w,    outw_bf, 393216);

    // 1. coupling: x_in += coef[z] * sec_bf @ cw^T   (in place, f32 out)
    gemm_bf16<4><<<dim3(4, 32, 3), blk, 0, stream>>>(
        (bf*)sec_bf, cw_bf, 512, 512, 512, 2097152L, 262144L,
        x_in, nullptr, 512, 2097152L, x_in, 2097152L, coef, 1, nullptr, 0L, 0);
    // 2. layernorm -> bf16
    ln_kernel<<<3*4096, blk, 0, stream>>>(x_in, xn_bf, norm_w, norm_b);
    // 3. in_proj halves -> bf16
    gemm_bf16<4><<<dim3(8, 32, 3), blk, 0, stream>>>(
        xn_bf, inw_bf, 512, 512, 512, 2097152L, 1048576L,
        nullptr, xcpre_bf, 1024, 4194304L, nullptr, 0L, nullptr, 0, nullptr, 0L, 0);
    gemm_bf16<4><<<dim3(8, 32, 3), blk, 0, stream>>>(
        xn_bf, inw_bf + 524288, 512, 512, 512, 2097152L, 1048576L,
        nullptr, z_bf, 1024, 4194304L, nullptr, 0L, nullptr, 0, nullptr, 0L, 0);
    // 4. conv + SiLU (bf16 -> bf16)
    conv_silu_kernel<<<6144, blk, 0, stream>>>(xcpre_bf, conv_w, conv_b, xc_bf);
    // 5. x_proj -> dbc bf16 (N=64 tile variant)
    gemm_bf16<2><<<dim3(1, 32, 3), blk, 0, stream>>>(
        xc_bf, xpw_bf, 1024, 1024, 1024, 4194304L, 65536L,
        nullptr, dbc_bf, 64, 262144L, nullptr, 0L, nullptr, 0, nullptr, 0L, 0);
    // 6. delta = softplus(dt @ dt_w^T + dt_b) -> bf16
    gemm_bf16<4><<<dim3(8, 32, 3), blk, 0, stream>>>(
        dbc_bf, dtw_bf, 32, 64, 32, 262144L, 32768L,
        nullptr, delta_bf, 1024, 4194304L, nullptr, 0L, nullptr, 0, dt_b, 1024L, 1);
    // 7. chunk-parallel scan
    scan_pass1_kernel<<<6*4*NCHUNK, blk, 0, stream>>>(delta_bf, xc_bf, dbc_bf, A_log, Fbuf, Dbuf);
    scan_pass2_kernel<<<(6*1024*16)/256, blk, 0, stream>>>(Fbuf, Dbuf);
    scan_pass3_kernel<<<6*4*NCHUNK, blk, 0, stream>>>(delta_bf, xc_bf, dbc_bf, z_bf,
                                                      A_log, D_skip, Fbuf, ybuf_bf);
    // 8. out_proj + residual -> d_out (f32)
    gemm_bf16<4><<<dim3(4, 32, 3), blk, 0, stream>>>(
        ybuf_bf, outw_bf, 1024, 1024, 1024, 4194304L, 524288L,
        out, nullptr, 512, 2097152L, x_in, 2097152L, nullptr, 0, nullptr, 0L, 0);
}

// Round 4
// 405.136 us; speedup vs baseline: 5.4298x; 1.2003x over previous
//
#include <hip/hip_runtime.h>
#include <hip/hip_bf16.h>

#define MODS 3
#define BSZ 2
#define LSEQ 2048
#define DMODEL 512
#define DINNER 1024
#define DTRANK 32
#define NSTATE 16
#define DCONV 4
#define MROWS (BSZ*LSEQ)   // 4096
#define NCHUNK 32
#define CHUNK 64           // LSEQ / NCHUNK

typedef __attribute__((ext_vector_type(8))) short short8v;
typedef __attribute__((ext_vector_type(4))) short short4v;
typedef __attribute__((ext_vector_type(2))) short short2v;
typedef __attribute__((ext_vector_type(4))) float f32x4;

__device__ __forceinline__ short f2bf(float x) {
    __hip_bfloat16 h = __float2bfloat16(x);
    return __builtin_bit_cast(short, h);
}
__device__ __forceinline__ float bf2f(short s) {
    return __uint_as_float(((unsigned)(unsigned short)s) << 16);
}
__device__ __forceinline__ void gl_lds16(const short* g, short* l) {
    __builtin_amdgcn_global_load_lds(
        (const __attribute__((address_space(1))) unsigned int*)g,
        (__attribute__((address_space(3))) unsigned int*)l, 16, 0, 0);
}

// ---------------- bf16 MFMA GEMM NT ----------------
template<int NJ>
__global__ __launch_bounds__(256) void gemm_bf16(
    const __hip_bfloat16* __restrict__ A_, const __hip_bfloat16* __restrict__ B_,
    int K, int lda, int ldb, long sA, long sB,
    float* __restrict__ Cf, __hip_bfloat16* __restrict__ Cb, int ldc, long sC,
    const float* __restrict__ res, long sRes,
    const float* __restrict__ coef_base, int coef_stride,
    const float* __restrict__ bias, long sBias, int act)
{
    constexpr int BN = NJ * 32;
    __shared__ alignas(16) short As[128 * 32];
    __shared__ alignas(16) short Bs[BN * 32];
    const int z = blockIdx.z;
    const int bm0 = blockIdx.y * 128;
    const int bn0 = blockIdx.x * BN;
    const short* Ag = (const short*)A_ + z * sA + (long)bm0 * lda;
    const short* Bg = (const short*)B_ + z * sB + (long)bn0 * ldb;
    const int tid = threadIdx.x;
    const int lane = tid & 63;
    const int w = tid >> 6;
    const int wr = w >> 1, wc = w & 1;
    const int lr = lane & 15, lk = (lane >> 4) * 8;
    const int arow = tid >> 2;
    const int aseg = (tid & 3) * 8;

    f32x4 acc[4][NJ];
    #pragma unroll
    for (int i = 0; i < 4; ++i)
        #pragma unroll
        for (int j = 0; j < NJ; ++j)
            acc[i][j] = (f32x4){0.f, 0.f, 0.f, 0.f};

    for (int k0 = 0; k0 < K; k0 += 32) {
        gl_lds16(Ag + (long)arow * lda + k0 + aseg, As + tid * 8);
        gl_lds16(Ag + (long)(64 + arow) * lda + k0 + aseg, As + 2048 + tid * 8);
        gl_lds16(Bg + (long)arow * ldb + k0 + aseg, Bs + tid * 8);
        if constexpr (NJ == 4)
            gl_lds16(Bg + (long)(64 + arow) * ldb + k0 + aseg, Bs + 2048 + tid * 8);
        __syncthreads();
        short8v af[4], bfr[NJ];
        #pragma unroll
        for (int i = 0; i < 4; ++i)
            af[i] = *(const short8v*)&As[(wr * 64 + i * 16 + lr) * 32 + lk];
        #pragma unroll
        for (int j = 0; j < NJ; ++j)
            bfr[j] = *(const short8v*)&Bs[(wc * NJ * 16 + j * 16 + lr) * 32 + lk];
        #pragma unroll
        for (int i = 0; i < 4; ++i)
            #pragma unroll
            for (int j = 0; j < NJ; ++j)
                acc[i][j] = __builtin_amdgcn_mfma_f32_16x16x32_bf16(af[i], bfr[j], acc[i][j], 0, 0, 0);
        __syncthreads();
    }

    const float alpha = coef_base ? coef_base[z * coef_stride] : 1.0f;
    const float* resz = res ? res + z * sRes : nullptr;
    const float* biasz = bias ? bias + z * sBias : nullptr;
    float* Cfz = Cf ? Cf + z * sC : nullptr;
    __hip_bfloat16* Cbz = Cb ? Cb + z * sC : nullptr;
    #pragma unroll
    for (int i = 0; i < 4; ++i) {
        #pragma unroll
        for (int r = 0; r < 4; ++r) {
            const int row = bm0 + wr * 64 + i * 16 + (lane >> 4) * 4 + r;
            #pragma unroll
            for (int j = 0; j < NJ; ++j) {
                const int col = bn0 + wc * NJ * 16 + j * 16 + lr;
                float val = acc[i][j][r];
                if (biasz) val += biasz[col];
                if (act == 1) val = (val > 20.f) ? val : log1pf(__expf(val));
                val *= alpha;
                if (resz) val += resz[(long)row * ldc + col];
                if (Cfz) Cfz[(long)row * ldc + col] = val;
                else     Cbz[(long)row * ldc + col] = __float2bfloat16(val);
            }
        }
    }
}

// ---------------- stack: x_in = [v;a;t] f32, sec_bf = [a;t;v] bf16 ----------------
__global__ __launch_bounds__(256) void stack_vat_kernel(
    const float* __restrict__ v, const float* __restrict__ a, const float* __restrict__ t,
    float* __restrict__ x_in, __hip_bfloat16* __restrict__ sec_bf)
{
    const long idx = (long)blockIdx.x * 256 + threadIdx.x;
    const int m = (int)(idx >> 19);
    const long off = idx & 524287;
    const float* prim = (m == 0) ? v : (m == 1) ? a : t;
    const float* sec  = (m == 0) ? a : (m == 1) ? t : v;
    float4 pv = ((const float4*)prim)[off];
    float4 sv = ((const float4*)sec)[off];
    ((float4*)x_in)[idx] = pv;
    short4v s;
    s.x = f2bf(sv.x); s.y = f2bf(sv.y); s.z = f2bf(sv.z); s.w = f2bf(sv.w);
    ((short4v*)sec_bf)[idx] = s;
}

// ---------------- fused weight conversions: 5 segments f32 -> bf16 ----------------
__global__ __launch_bounds__(256) void cvt_all_kernel(
    const float* __restrict__ s0, __hip_bfloat16* __restrict__ d0, int n0,
    const float* __restrict__ s1, __hip_bfloat16* __restrict__ d1, int n1,
    const float* __restrict__ s2, __hip_bfloat16* __restrict__ d2, int n2,
    const float* __restrict__ s3, __hip_bfloat16* __restrict__ d3, int n3,
    const float* __restrict__ s4, __hip_bfloat16* __restrict__ d4, int n4)
{
    int idx = blockIdx.x * 256 + threadIdx.x;   // float4 units
    const float* s; __hip_bfloat16* d; int off = idx;
    if      (off < n0)                  { s = s0; d = d0; }
    else if ((off -= n0) < n1)          { s = s1; d = d1; }
    else if ((off -= n1) < n2)          { s = s2; d = d2; }
    else if ((off -= n2) < n3)          { s = s3; d = d3; }
    else if ((off -= n3) < n4)          { s = s4; d = d4; }
    else return;
    float4 vv = ((const float4*)s)[off];
    short4v o;
    o.x = f2bf(vv.x); o.y = f2bf(vv.y); o.z = f2bf(vv.z); o.w = f2bf(vv.w);
    ((short4v*)d)[off] = o;
}

// ---------------- conv weight transpose: cw[m][c][k] -> cwT[m][k][c] (f32) ----------------
__global__ __launch_bounds__(256) void conv_wt_kernel(const float* __restrict__ cw,
                                                      float* __restrict__ cwT)
{
    const int idx = blockIdx.x * 256 + threadIdx.x;   // < 3*1024*4
    if (idx >= MODS * DINNER * DCONV) return;
    const int k = idx & 3;
    const int c = (idx >> 2) & 1023;
    const int m = idx >> 12;
    cwT[(m * DCONV + k) * DINNER + c] = cw[idx];
}

// ---------------- LayerNorm: f32 in -> bf16 out ----------------
__global__ __launch_bounds__(256) void ln_kernel(const float* __restrict__ x, __hip_bfloat16* __restrict__ xn,
                                                 const float* __restrict__ nw, const float* __restrict__ nb)
{
    const int row = blockIdx.x;
    const int m = row >> 12;
    const int tid = threadIdx.x;
    const float2 v = *reinterpret_cast<const float2*>(x + (long)row * DMODEL + tid * 2);
    float s = v.x + v.y;
    float sq = v.x * v.x + v.y * v.y;
    #pragma unroll
    for (int off = 32; off > 0; off >>= 1) {
        s  += __shfl_down(s, off);
        sq += __shfl_down(sq, off);
    }
    __shared__ float ws_s[4], ws_q[4];
    const int wid = tid >> 6, lane = tid & 63;
    if (lane == 0) { ws_s[wid] = s; ws_q[wid] = sq; }
    __syncthreads();
    if (tid == 0) {
        float ts = ws_s[0] + ws_s[1] + ws_s[2] + ws_s[3];
        float tq = ws_q[0] + ws_q[1] + ws_q[2] + ws_q[3];
        float mu = ts / DMODEL;
        float var = tq / DMODEL - mu * mu;
        ws_s[0] = mu;
        ws_q[0] = rsqrtf(var + 1e-5f);
    }
    __syncthreads();
    const float mu = ws_s[0], rstd = ws_q[0];
    const int e0 = tid * 2;
    float2 w  = *reinterpret_cast<const float2*>(nw + m * DMODEL + e0);
    float2 bb = *reinterpret_cast<const float2*>(nb + m * DMODEL + e0);
    short2v o;
    o.x = f2bf((v.x - mu) * rstd * w.x + bb.x);
    o.y = f2bf((v.y - mu) * rstd * w.y + bb.y);
    *reinterpret_cast<short2v*>((short*)xn + (long)row * DMODEL + e0) = o;
}

// ---------------- depthwise causal conv(4) + SiLU ----------------
// thread = 8 channels x 8 timesteps; transposed weights (coalesced); sliding register window
__global__ __launch_bounds__(256) void conv_silu_kernel(const __hip_bfloat16* __restrict__ xin,
    const float* __restrict__ cwT, const float* __restrict__ cb, __hip_bfloat16* __restrict__ xc)
{
    const int idx = blockIdx.x * 256 + threadIdx.x;   // < 6*256*128 = 196608
    const int c8 = idx & 127;
    const int lt = (idx >> 7) & 255;
    const int mb = idx >> 15;
    const int m  = mb >> 1;
    const int c0 = c8 * 8;
    const int l0 = lt * 8;

    float4 wlo[DCONV], whi[DCONV];
    #pragma unroll
    for (int k = 0; k < DCONV; ++k) {
        wlo[k] = *(const float4*)&cwT[(m * DCONV + k) * DINNER + c0];
        whi[k] = *(const float4*)&cwT[(m * DCONV + k) * DINNER + c0 + 4];
    }
    const float4 blo = *(const float4*)&cb[m * DINNER + c0];
    const float4 bhi = *(const float4*)&cb[m * DINNER + c0 + 4];

    const short* base = (const short*)xin + (long)mb * LSEQ * DINNER + c0;
    short* obase = (short*)xc + (long)mb * LSEQ * DINNER + c0;

    short8v r0 = {}, r1 = {}, r2 = {};
    if (l0 >= 3) {
        r0 = *(const short8v*)(base + (long)(l0 - 3) * DINNER);
        r1 = *(const short8v*)(base + (long)(l0 - 2) * DINNER);
        r2 = *(const short8v*)(base + (long)(l0 - 1) * DINNER);
    } else {
        if (l0 - 3 >= 0) r0 = *(const short8v*)(base + (long)(l0 - 3) * DINNER);
        if (l0 - 2 >= 0) r1 = *(const short8v*)(base + (long)(l0 - 2) * DINNER);
        if (l0 - 1 >= 0) r2 = *(const short8v*)(base + (long)(l0 - 1) * DINNER);
    }

    #pragma unroll
    for (int i = 0; i < 8; ++i) {
        const short8v cur = *(const short8v*)(base + (long)(l0 + i) * DINNER);
        float acc[8];
        #pragma unroll
        for (int j = 0; j < 4; ++j) {
            acc[j]     = ((const float*)&blo)[j];
            acc[4 + j] = ((const float*)&bhi)[j];
        }
        #pragma unroll
        for (int j = 0; j < 8; ++j) {
            const float w0 = (j < 4) ? ((const float*)&wlo[0])[j] : ((const float*)&whi[0])[j - 4];
            const float w1 = (j < 4) ? ((const float*)&wlo[1])[j] : ((const float*)&whi[1])[j - 4];
            const float w2 = (j < 4) ? ((const float*)&wlo[2])[j] : ((const float*)&whi[2])[j - 4];
            const float w3 = (j < 4) ? ((const float*)&wlo[3])[j] : ((const float*)&whi[3])[j - 4];
            acc[j] += w0 * bf2f(r0[j]) + w1 * bf2f(r1[j]) + w2 * bf2f(r2[j]) + w3 * bf2f(cur[j]);
        }
        short8v o;
        #pragma unroll
        for (int j = 0; j < 8; ++j) {
            const float sg = 1.f / (1.f + __expf(-acc[j]));
            o[j] = f2bf(acc[j] * sg);
        }
        *(short8v*)(obase + (long)(l0 + i) * DINNER) = o;
        r0 = r1; r1 = r2; r2 = cur;
    }
}

// ---------------- chunk-parallel selective scan (bf16 activations) ----------------
__global__ __launch_bounds__(256) void scan_pass1_kernel(
    const __hip_bfloat16* __restrict__ delta, const __hip_bfloat16* __restrict__ xc,
    const __hip_bfloat16* __restrict__ dbc, const float* __restrict__ A_log,
    float* __restrict__ Fbuf, float* __restrict__ Dbuf)
{
    const int bx = blockIdx.x;
    const int chunk = bx & (NCHUNK - 1);
    const int cg = (bx >> 5) & 3;
    const int mb = bx >> 7;
    const int m = mb >> 1, b = mb & 1;
    const int tid = threadIdx.x;
    const int c = cg * 256 + tid;

    float A[NSTATE];
    #pragma unroll
    for (int n = 0; n < NSTATE; ++n)
        A[n] = -__expf(A_log[((long)m * DINNER + c) * NSTATE + n]);
    float h[NSTATE] = {};
    float P[NSTATE];
    #pragma unroll
    for (int n = 0; n < NSTATE; ++n) P[n] = 1.f;

    __shared__ float sB[CHUNK][NSTATE];
    const short* dbc_mb = (const short*)dbc + (long)m * MROWS * 64 + (long)b * LSEQ * 64;
    const int t0 = chunk * CHUNK;
    for (int i = tid; i < CHUNK * NSTATE; i += 256) {
        int tt = i >> 4, j = i & 15;
        sB[tt][j] = bf2f(dbc_mb[(long)(t0 + tt) * 64 + 32 + j]);
    }
    __syncthreads();

    const short* dp = (const short*)delta;
    const short* up = (const short*)xc;
    const long base = ((long)mb * LSEQ + t0) * DINNER + c;
    #pragma unroll 4
    for (int tt = 0; tt < CHUNK; ++tt) {
        const float d = bf2f(dp[base + (long)tt * DINNER]);
        const float u = bf2f(up[base + (long)tt * DINNER]);
        const float du = d * u;
        #pragma unroll
        for (int n = 0; n < NSTATE; ++n) {
            float e = __expf(d * A[n]);
            h[n] = e * h[n] + du * sB[tt][n];
            P[n] *= e;
        }
    }
    const long o = (((long)mb * NCHUNK + chunk) * DINNER + c) * NSTATE;
    #pragma unroll
    for (int n = 0; n < NSTATE; ++n) { Fbuf[o + n] = h[n]; Dbuf[o + n] = P[n]; }
}

__global__ __launch_bounds__(256) void scan_pass2_kernel(float* __restrict__ Fbuf,
                                                         const float* __restrict__ Dbuf)
{
    const long idx = (long)blockIdx.x * 256 + threadIdx.x;
    const int mb = (int)(idx >> 14);
    const int cn = (int)(idx & 16383);
    float run = 0.f;
    for (int k = 0; k < NCHUNK; ++k) {
        const long o = ((long)mb * NCHUNK + k) * 16384 + cn;
        const float f = Fbuf[o];
        const float p = Dbuf[o];
        Fbuf[o] = run;
        run = p * run + f;
    }
}

__global__ __launch_bounds__(256) void scan_pass3_kernel(
    const __hip_bfloat16* __restrict__ delta, const __hip_bfloat16* __restrict__ xc,
    const __hip_bfloat16* __restrict__ dbc, const __hip_bfloat16* __restrict__ zbuf,
    const float* __restrict__ A_log, const float* __restrict__ D_skip,
    const float* __restrict__ Hin, __hip_bfloat16* __restrict__ ybuf)
{
    const int bx = blockIdx.x;
    const int chunk = bx & (NCHUNK - 1);
    const int cg = (bx >> 5) & 3;
    const int mb = bx >> 7;
    const int m = mb >> 1, b = mb & 1;
    const int tid = threadIdx.x;
    const int c = cg * 256 + tid;

    float A[NSTATE];
    #pragma unroll
    for (int n = 0; n < NSTATE; ++n)
        A[n] = -__expf(A_log[((long)m * DINNER + c) * NSTATE + n]);
    const float Dsk = D_skip[m * DINNER + c];

    float h[NSTATE];
    const long ho = (((long)mb * NCHUNK + chunk) * DINNER + c) * NSTATE;
    #pragma unroll
    for (int n = 0; n < NSTATE; ++n) h[n] = Hin[ho + n];

    __shared__ float sBC[CHUNK][2 * NSTATE];
    const short* dbc_mb = (const short*)dbc + (long)m * MROWS * 64 + (long)b * LSEQ * 64;
    const int t0 = chunk * CHUNK;
    for (int i = tid; i < CHUNK * 2 * NSTATE; i += 256) {
        int tt = i >> 5, j = i & 31;
        sBC[tt][j] = bf2f(dbc_mb[(long)(t0 + tt) * 64 + 32 + j]);
    }
    __syncthreads();

    const short* dp = (const short*)delta;
    const short* up = (const short*)xc;
    const short* zp = (const short*)zbuf;
    short* yp = (short*)ybuf;
    const long base = ((long)mb * LSEQ + t0) * DINNER + c;
    #pragma unroll 4
    for (int tt = 0; tt < CHUNK; ++tt) {
        const long idx = base + (long)tt * DINNER;
        const float d = bf2f(dp[idx]);
        const float u = bf2f(up[idx]);
        const float zv = bf2f(zp[idx]);
        const float du = d * u;
        float y = 0.f;
        #pragma unroll
        for (int n = 0; n < NSTATE; ++n) {
            float e = __expf(d * A[n]);
            h[n] = e * h[n] + du * sBC[tt][n];
            y += h[n] * sBC[tt][16 + n];
        }
        y += u * Dsk;
        const float sg = 1.f / (1.f + __expf(-zv));
        yp[idx] = f2bf(y * (zv * sg));
    }
}

extern "C" void kernel_launch(void* const* d_in, const int* in_sizes, int n_in,
                              void* d_out, int out_size, void* d_ws, size_t ws_size,
                              hipStream_t stream)
{
    const float* v       = (const float*)d_in[0];
    const float* a       = (const float*)d_in[1];
    const float* t       = (const float*)d_in[2];
    const float* norm_w  = (const float*)d_in[3];
    const float* norm_b  = (const float*)d_in[4];
    const float* in_w    = (const float*)d_in[5];
    const float* conv_w  = (const float*)d_in[6];
    const float* conv_b  = (const float*)d_in[7];
    const float* xproj_w = (const float*)d_in[8];
    const float* dt_w    = (const float*)d_in[9];
    const float* dt_b    = (const float*)d_in[10];
    const float* A_log   = (const float*)d_in[11];
    const float* D_skip  = (const float*)d_in[12];
    const float* out_w   = (const float*)d_in[13];
    const float* couple_w= (const float*)d_in[14];
    const float* coef    = (const float*)d_in[15];
    float* out = (float*)d_out;

    typedef __hip_bfloat16 bf;
    float* x_in   = (float*)d_ws;                       // [3][4096][512] f32
    bf* xn_bf     = (bf*)(x_in + 6291456);              // [3][4096][512]
    bf* sec_bf    = xn_bf + 6291456;                    // [3][4096][512]
    bf* xcpre_bf  = sec_bf + 6291456;                   // [3][4096][1024]  (later reused as ybuf)
    bf* z_bf      = xcpre_bf + 12582912;                // [3][4096][1024]
    bf* xc_bf     = z_bf + 12582912;                    // [3][4096][1024]
    bf* delta_bf  = xc_bf + 12582912;                   // [3][4096][1024]
    bf* dbc_bf    = delta_bf + 12582912;                // [3][4096][64]
    bf* cw_bf     = dbc_bf + 786432;                    // [3][512][512]
    bf* inw_bf    = cw_bf + 786432;                     // [3][2048][512]
    bf* xpw_bf    = inw_bf + 3145728;                   // [3][64][1024]
    bf* dtw_bf    = xpw_bf + 196608;                    // [3][1024][32]
    bf* outw_bf   = dtw_bf + 98304;                     // [3][512][1024]
    float* cwT    = (float*)(outw_bf + 1572864);        // [3][4][1024] f32
    bf* ybuf_bf   = xcpre_bf;                           // alias (xcpre dead after conv)

    float* Fbuf = out;                                  // [6][32][1024][16] in d_out
    float* Dbuf = out + 3145728;

    dim3 blk(256);

    // 0. conversions (one fused kernel) + conv-weight transpose + stack
    stack_vat_kernel<<<6144, blk, 0, stream>>>(v, a, t, x_in, sec_bf);
    cvt_all_kernel<<<(196608 + 786432 + 49152 + 24576 + 393216 + 255) / 256, blk, 0, stream>>>(
        couple_w, cw_bf, 196608, in_w, inw_bf, 786432, xproj_w, xpw_bf, 49152,
        dt_w, dtw_bf, 24576, out_w, outw_bf, 393216);
    conv_wt_kernel<<<48, blk, 0, stream>>>(conv_w, cwT);

    // 1. coupling: x_in += coef[z] * sec_bf @ cw^T   (in place, f32 out)
    gemm_bf16<4><<<dim3(4, 32, 3), blk, 0, stream>>>(
        (bf*)sec_bf, cw_bf, 512, 512, 512, 2097152L, 262144L,
        x_in, nullptr, 512, 2097152L, x_in, 2097152L, coef, 1, nullptr, 0L, 0);
    // 2. layernorm -> bf16
    ln_kernel<<<3*4096, blk, 0, stream>>>(x_in, xn_bf, norm_w, norm_b);
    // 3. in_proj halves -> bf16
    gemm_bf16<4><<<dim3(8, 32, 3), blk, 0, stream>>>(
        xn_bf, inw_bf, 512, 512, 512, 2097152L, 1048576L,
        nullptr, xcpre_bf, 1024, 4194304L, nullptr, 0L, nullptr, 0, nullptr, 0L, 0);
    gemm_bf16<4><<<dim3(8, 32, 3), blk, 0, stream>>>(
        xn_bf, inw_bf + 524288, 512, 512, 512, 2097152L, 1048576L,
        nullptr, z_bf, 1024, 4194304L, nullptr, 0L, nullptr, 0, nullptr, 0L, 0);
    // 4. conv + SiLU (bf16 -> bf16), transposed weights, 8 rows/thread
    conv_silu_kernel<<<768, blk, 0, stream>>>(xcpre_bf, cwT, conv_b, xc_bf);
    // 5. x_proj -> dbc bf16
    gemm_bf16<2><<<dim3(1, 32, 3), blk, 0, stream>>>(
        xc_bf, xpw_bf, 1024, 1024, 1024, 4194304L, 65536L,
        nullptr, dbc_bf, 64, 262144L, nullptr, 0L, nullptr, 0, nullptr, 0L, 0);
    // 6. delta = softplus(dt @ dt_w^T + dt_b) -> bf16
    gemm_bf16<4><<<dim3(8, 32, 3), blk, 0, stream>>>(
        dbc_bf, dtw_bf, 32, 64, 32, 262144L, 32768L,
        nullptr, delta_bf, 1024, 4194304L, nullptr, 0L, nullptr, 0, dt_b, 1024L, 1);
    // 7. chunk-parallel scan
    scan_pass1_kernel<<<6*4*NCHUNK, blk, 0, stream>>>(delta_bf, xc_bf, dbc_bf, A_log, Fbuf, Dbuf);
    scan_pass2_kernel<<<(6*1024*16)/256, blk, 0, stream>>>(Fbuf, Dbuf);
    scan_pass3_kernel<<<6*4*NCHUNK, blk, 0, stream>>>(delta_bf, xc_bf, dbc_bf, z_bf,
                                                      A_log, D_skip, Fbuf, ybuf_bf);
    // 8. out_proj + residual -> d_out (f32)
    gemm_bf16<4><<<dim3(4, 32, 3), blk, 0, stream>>>(
        ybuf_bf, outw_bf, 1024, 1024, 1024, 4194304L, 524288L,
        out, nullptr, 512, 2097152L, x_in, 2097152L, nullptr, 0, nullptr, 0L, 0);
}

// Round 5
// 362.144 us; speedup vs baseline: 6.0745x; 1.1187x over previous
//
#include <hip/hip_runtime.h>
#include <hip/hip_bf16.h>

#define MODS 3
#define BSZ 2
#define LSEQ 2048
#define DMODEL 512
#define DINNER 1024
#define DTRANK 32
#define NSTATE 16
#define DCONV 4
#define MROWS (BSZ*LSEQ)   // 4096
#define NCHUNK 64
#define CHUNK 32           // LSEQ / NCHUNK

#define LOG2E 1.44269504088896f
#define LN2   0.69314718055995f

typedef __attribute__((ext_vector_type(8))) short short8v;
typedef __attribute__((ext_vector_type(4))) short short4v;
typedef __attribute__((ext_vector_type(2))) short short2v;
typedef __attribute__((ext_vector_type(4))) float f32x4;

#if __has_builtin(__builtin_amdgcn_exp2f)
#define EXP2F __builtin_amdgcn_exp2f
#else
#define EXP2F exp2f
#endif
#if __has_builtin(__builtin_amdgcn_rcpf)
#define RCPF __builtin_amdgcn_rcpf
#else
#define RCPF(x) (1.0f / (x))
#endif

__device__ __forceinline__ short f2bf(float x) {
    __hip_bfloat16 h = __float2bfloat16(x);
    return __builtin_bit_cast(short, h);
}
__device__ __forceinline__ float bf2f(short s) {
    return __uint_as_float(((unsigned)(unsigned short)s) << 16);
}
__device__ __forceinline__ void gl_lds16(const short* g, short* l) {
    __builtin_amdgcn_global_load_lds(
        (const __attribute__((address_space(1))) unsigned int*)g,
        (__attribute__((address_space(3))) unsigned int*)l, 16, 0, 0);
}
__device__ __forceinline__ float sigmoid_f(float x) {
    return RCPF(1.f + EXP2F(-x * LOG2E));
}

// ---------------- bf16 MFMA GEMM NT ----------------
template<int NJ>
__global__ __launch_bounds__(256) void gemm_bf16(
    const __hip_bfloat16* __restrict__ A_, const __hip_bfloat16* __restrict__ B_,
    int K, int lda, int ldb, long sA, long sB,
    float* __restrict__ Cf, __hip_bfloat16* __restrict__ Cb, int ldc, long sC,
    const float* __restrict__ res, long sRes,
    const float* __restrict__ coef_base, int coef_stride,
    const float* __restrict__ bias, long sBias, int act)
{
    constexpr int BN = NJ * 32;
    __shared__ alignas(16) short As[128 * 32];
    __shared__ alignas(16) short Bs[BN * 32];
    const int z = blockIdx.z;
    const int bm0 = blockIdx.y * 128;
    const int bn0 = blockIdx.x * BN;
    const short* Ag = (const short*)A_ + z * sA + (long)bm0 * lda;
    const short* Bg = (const short*)B_ + z * sB + (long)bn0 * ldb;
    const int tid = threadIdx.x;
    const int lane = tid & 63;
    const int w = tid >> 6;
    const int wr = w >> 1, wc = w & 1;
    const int lr = lane & 15, lk = (lane >> 4) * 8;
    const int arow = tid >> 2;
    const int aseg = (tid & 3) * 8;

    f32x4 acc[4][NJ];
    #pragma unroll
    for (int i = 0; i < 4; ++i)
        #pragma unroll
        for (int j = 0; j < NJ; ++j)
            acc[i][j] = (f32x4){0.f, 0.f, 0.f, 0.f};

    for (int k0 = 0; k0 < K; k0 += 32) {
        gl_lds16(Ag + (long)arow * lda + k0 + aseg, As + tid * 8);
        gl_lds16(Ag + (long)(64 + arow) * lda + k0 + aseg, As + 2048 + tid * 8);
        gl_lds16(Bg + (long)arow * ldb + k0 + aseg, Bs + tid * 8);
        if constexpr (NJ == 4)
            gl_lds16(Bg + (long)(64 + arow) * ldb + k0 + aseg, Bs + 2048 + tid * 8);
        __syncthreads();
        short8v af[4], bfr[NJ];
        #pragma unroll
        for (int i = 0; i < 4; ++i)
            af[i] = *(const short8v*)&As[(wr * 64 + i * 16 + lr) * 32 + lk];
        #pragma unroll
        for (int j = 0; j < NJ; ++j)
            bfr[j] = *(const short8v*)&Bs[(wc * NJ * 16 + j * 16 + lr) * 32 + lk];
        #pragma unroll
        for (int i = 0; i < 4; ++i)
            #pragma unroll
            for (int j = 0; j < NJ; ++j)
                acc[i][j] = __builtin_amdgcn_mfma_f32_16x16x32_bf16(af[i], bfr[j], acc[i][j], 0, 0, 0);
        __syncthreads();
    }

    const float alpha = coef_base ? coef_base[z * coef_stride] : 1.0f;
    const float* resz = res ? res + z * sRes : nullptr;
    const float* biasz = bias ? bias + z * sBias : nullptr;
    float* Cfz = Cf ? Cf + z * sC : nullptr;
    __hip_bfloat16* Cbz = Cb ? Cb + z * sC : nullptr;
    #pragma unroll
    for (int i = 0; i < 4; ++i) {
        #pragma unroll
        for (int r = 0; r < 4; ++r) {
            const int row = bm0 + wr * 64 + i * 16 + (lane >> 4) * 4 + r;
            #pragma unroll
            for (int j = 0; j < NJ; ++j) {
                const int col = bn0 + wc * NJ * 16 + j * 16 + lr;
                float val = acc[i][j][r];
                if (biasz) val += biasz[col];
                if (act == 1)
                    val = (val > 20.f) ? val : LN2 * __log2f(1.f + EXP2F(val * LOG2E));
                val *= alpha;
                if (resz) val += resz[(long)row * ldc + col];
                if (Cfz) Cfz[(long)row * ldc + col] = val;
                else     Cbz[(long)row * ldc + col] = __float2bfloat16(val);
            }
        }
    }
}

// ---------------- stack: x_in = [v;a;t] f32, sec_bf = [a;t;v] bf16 ----------------
__global__ __launch_bounds__(256) void stack_vat_kernel(
    const float* __restrict__ v, const float* __restrict__ a, const float* __restrict__ t,
    float* __restrict__ x_in, __hip_bfloat16* __restrict__ sec_bf)
{
    const long idx = (long)blockIdx.x * 256 + threadIdx.x;
    const int m = (int)(idx >> 19);
    const long off = idx & 524287;
    const float* prim = (m == 0) ? v : (m == 1) ? a : t;
    const float* sec  = (m == 0) ? a : (m == 1) ? t : v;
    float4 pv = ((const float4*)prim)[off];
    float4 sv = ((const float4*)sec)[off];
    ((float4*)x_in)[idx] = pv;
    short4v s;
    s.x = f2bf(sv.x); s.y = f2bf(sv.y); s.z = f2bf(sv.z); s.w = f2bf(sv.w);
    ((short4v*)sec_bf)[idx] = s;
}

// ---------------- fused weight conversions: 5 segments f32 -> bf16 ----------------
__global__ __launch_bounds__(256) void cvt_all_kernel(
    const float* __restrict__ s0, __hip_bfloat16* __restrict__ d0, int n0,
    const float* __restrict__ s1, __hip_bfloat16* __restrict__ d1, int n1,
    const float* __restrict__ s2, __hip_bfloat16* __restrict__ d2, int n2,
    const float* __restrict__ s3, __hip_bfloat16* __restrict__ d3, int n3,
    const float* __restrict__ s4, __hip_bfloat16* __restrict__ d4, int n4)
{
    int idx = blockIdx.x * 256 + threadIdx.x;
    const float* s; __hip_bfloat16* d; int off = idx;
    if      (off < n0)                  { s = s0; d = d0; }
    else if ((off -= n0) < n1)          { s = s1; d = d1; }
    else if ((off -= n1) < n2)          { s = s2; d = d2; }
    else if ((off -= n2) < n3)          { s = s3; d = d3; }
    else if ((off -= n3) < n4)          { s = s4; d = d4; }
    else return;
    float4 vv = ((const float4*)s)[off];
    short4v o;
    o.x = f2bf(vv.x); o.y = f2bf(vv.y); o.z = f2bf(vv.z); o.w = f2bf(vv.w);
    ((short4v*)d)[off] = o;
}

// ---------------- conv weight transpose: cw[m][c][k] -> cwT[m][k][c] (f32) ----------------
__global__ __launch_bounds__(256) void conv_wt_kernel(const float* __restrict__ cw,
                                                      float* __restrict__ cwT)
{
    const int idx = blockIdx.x * 256 + threadIdx.x;
    if (idx >= MODS * DINNER * DCONV) return;
    const int k = idx & 3;
    const int c = (idx >> 2) & 1023;
    const int m = idx >> 12;
    cwT[(m * DCONV + k) * DINNER + c] = cw[idx];
}

// ---------------- LayerNorm: f32 in -> bf16 out ----------------
__global__ __launch_bounds__(256) void ln_kernel(const float* __restrict__ x, __hip_bfloat16* __restrict__ xn,
                                                 const float* __restrict__ nw, const float* __restrict__ nb)
{
    const int row = blockIdx.x;
    const int m = row >> 12;
    const int tid = threadIdx.x;
    const float2 v = *reinterpret_cast<const float2*>(x + (long)row * DMODEL + tid * 2);
    float s = v.x + v.y;
    float sq = v.x * v.x + v.y * v.y;
    #pragma unroll
    for (int off = 32; off > 0; off >>= 1) {
        s  += __shfl_down(s, off);
        sq += __shfl_down(sq, off);
    }
    __shared__ float ws_s[4], ws_q[4];
    const int wid = tid >> 6, lane = tid & 63;
    if (lane == 0) { ws_s[wid] = s; ws_q[wid] = sq; }
    __syncthreads();
    if (tid == 0) {
        float ts = ws_s[0] + ws_s[1] + ws_s[2] + ws_s[3];
        float tq = ws_q[0] + ws_q[1] + ws_q[2] + ws_q[3];
        float mu = ts / DMODEL;
        float var = tq / DMODEL - mu * mu;
        ws_s[0] = mu;
        ws_q[0] = rsqrtf(var + 1e-5f);
    }
    __syncthreads();
    const float mu = ws_s[0], rstd = ws_q[0];
    const int e0 = tid * 2;
    float2 w  = *reinterpret_cast<const float2*>(nw + m * DMODEL + e0);
    float2 bb = *reinterpret_cast<const float2*>(nb + m * DMODEL + e0);
    short2v o;
    o.x = f2bf((v.x - mu) * rstd * w.x + bb.x);
    o.y = f2bf((v.y - mu) * rstd * w.y + bb.y);
    *reinterpret_cast<short2v*>((short*)xn + (long)row * DMODEL + e0) = o;
}

// ---------------- depthwise causal conv(4) + SiLU ----------------
__global__ __launch_bounds__(256) void conv_silu_kernel(const __hip_bfloat16* __restrict__ xin,
    const float* __restrict__ cwT, const float* __restrict__ cb, __hip_bfloat16* __restrict__ xc)
{
    const int idx = blockIdx.x * 256 + threadIdx.x;   // < 6*256*128 = 196608
    const int c8 = idx & 127;
    const int lt = (idx >> 7) & 255;
    const int mb = idx >> 15;
    const int m  = mb >> 1;
    const int c0 = c8 * 8;
    const int l0 = lt * 8;

    float4 wlo[DCONV], whi[DCONV];
    #pragma unroll
    for (int k = 0; k < DCONV; ++k) {
        wlo[k] = *(const float4*)&cwT[(m * DCONV + k) * DINNER + c0];
        whi[k] = *(const float4*)&cwT[(m * DCONV + k) * DINNER + c0 + 4];
    }
    const float4 blo = *(const float4*)&cb[m * DINNER + c0];
    const float4 bhi = *(const float4*)&cb[m * DINNER + c0 + 4];

    const short* base = (const short*)xin + (long)mb * LSEQ * DINNER + c0;
    short* obase = (short*)xc + (long)mb * LSEQ * DINNER + c0;

    short8v r0 = {}, r1 = {}, r2 = {};
    if (l0 - 3 >= 0) r0 = *(const short8v*)(base + (long)(l0 - 3) * DINNER);
    if (l0 - 2 >= 0) r1 = *(const short8v*)(base + (long)(l0 - 2) * DINNER);
    if (l0 - 1 >= 0) r2 = *(const short8v*)(base + (long)(l0 - 1) * DINNER);

    #pragma unroll
    for (int i = 0; i < 8; ++i) {
        const short8v cur = *(const short8v*)(base + (long)(l0 + i) * DINNER);
        float acc[8];
        #pragma unroll
        for (int j = 0; j < 4; ++j) {
            acc[j]     = ((const float*)&blo)[j];
            acc[4 + j] = ((const float*)&bhi)[j];
        }
        #pragma unroll
        for (int j = 0; j < 8; ++j) {
            const float w0 = (j < 4) ? ((const float*)&wlo[0])[j] : ((const float*)&whi[0])[j - 4];
            const float w1 = (j < 4) ? ((const float*)&wlo[1])[j] : ((const float*)&whi[1])[j - 4];
            const float w2 = (j < 4) ? ((const float*)&wlo[2])[j] : ((const float*)&whi[2])[j - 4];
            const float w3 = (j < 4) ? ((const float*)&wlo[3])[j] : ((const float*)&whi[3])[j - 4];
            acc[j] += w0 * bf2f(r0[j]) + w1 * bf2f(r1[j]) + w2 * bf2f(r2[j]) + w3 * bf2f(cur[j]);
        }
        short8v o;
        #pragma unroll
        for (int j = 0; j < 8; ++j)
            o[j] = f2bf(acc[j] * sigmoid_f(acc[j]));
        *(short8v*)(obase + (long)(l0 + i) * DINNER) = o;
        r0 = r1; r1 = r2; r2 = cur;
    }
}

// ---------------- chunk-parallel selective scan (bf16 activations) ----------------
// A2[n] = -exp(A_log)*log2e so e = exp2(d*A2[n]) is one v_exp.
__global__ __launch_bounds__(256) void scan_pass1_kernel(
    const __hip_bfloat16* __restrict__ delta, const __hip_bfloat16* __restrict__ xc,
    const __hip_bfloat16* __restrict__ dbc, const float* __restrict__ A_log,
    float* __restrict__ Fbuf, float* __restrict__ Dbuf)
{
    const int bx = blockIdx.x;             // mb(6) x cg(4) x chunk(64)
    const int chunk = bx & (NCHUNK - 1);
    const int cg = (bx >> 6) & 3;
    const int mb = bx >> 8;
    const int m = mb >> 1, b = mb & 1;
    const int tid = threadIdx.x;
    const int c = cg * 256 + tid;

    float A2[NSTATE];
    #pragma unroll
    for (int n = 0; n < NSTATE; ++n)
        A2[n] = -EXP2F(A_log[((long)m * DINNER + c) * NSTATE + n] * LOG2E) * LOG2E;
    float h[NSTATE] = {};
    float sum_d = 0.f;

    __shared__ float sB[CHUNK][NSTATE];
    const short* dbc_mb = (const short*)dbc + (long)m * MROWS * 64 + (long)b * LSEQ * 64;
    const int t0 = chunk * CHUNK;
    for (int i = tid; i < CHUNK * NSTATE; i += 256) {
        int tt = i >> 4, j = i & 15;
        sB[tt][j] = bf2f(dbc_mb[(long)(t0 + tt) * 64 + 32 + j]);
    }
    __syncthreads();

    const short* dp = (const short*)delta;
    const short* up = (const short*)xc;
    const long base = ((long)mb * LSEQ + t0) * DINNER + c;
    #pragma unroll 4
    for (int tt = 0; tt < CHUNK; ++tt) {
        const float d = bf2f(dp[base + (long)tt * DINNER]);
        const float u = bf2f(up[base + (long)tt * DINNER]);
        const float du = d * u;
        sum_d += d;
        #pragma unroll
        for (int n = 0; n < NSTATE; ++n) {
            float e = EXP2F(d * A2[n]);
            h[n] = e * h[n] + du * sB[tt][n];
        }
    }
    const long o = (((long)mb * NCHUNK + chunk) * DINNER + c) * NSTATE;
    #pragma unroll
    for (int n = 0; n < NSTATE; ++n) {
        Fbuf[o + n] = h[n];
        Dbuf[o + n] = EXP2F(sum_d * A2[n]);   // = prod_t exp(d_t * A[n])
    }
}

__global__ __launch_bounds__(256) void scan_pass2_kernel(float* __restrict__ Fbuf,
                                                         const float* __restrict__ Dbuf)
{
    const long idx = (long)blockIdx.x * 256 + threadIdx.x;  // < 6*1024*16
    const int mb = (int)(idx >> 14);
    const int cn = (int)(idx & 16383);
    float run = 0.f;
    for (int k = 0; k < NCHUNK; ++k) {
        const long o = ((long)mb * NCHUNK + k) * 16384 + cn;
        const float f = Fbuf[o];
        const float p = Dbuf[o];
        Fbuf[o] = run;
        run = p * run + f;
    }
}

__global__ __launch_bounds__(256) void scan_pass3_kernel(
    const __hip_bfloat16* __restrict__ delta, const __hip_bfloat16* __restrict__ xc,
    const __hip_bfloat16* __restrict__ dbc, const __hip_bfloat16* __restrict__ zbuf,
    const float* __restrict__ A_log, const float* __restrict__ D_skip,
    const float* __restrict__ Hin, __hip_bfloat16* __restrict__ ybuf)
{
    const int bx = blockIdx.x;
    const int chunk = bx & (NCHUNK - 1);
    const int cg = (bx >> 6) & 3;
    const int mb = bx >> 8;
    const int m = mb >> 1, b = mb & 1;
    const int tid = threadIdx.x;
    const int c = cg * 256 + tid;

    float A2[NSTATE];
    #pragma unroll
    for (int n = 0; n < NSTATE; ++n)
        A2[n] = -EXP2F(A_log[((long)m * DINNER + c) * NSTATE + n] * LOG2E) * LOG2E;
    const float Dsk = D_skip[m * DINNER + c];

    float h[NSTATE];
    const long ho = (((long)mb * NCHUNK + chunk) * DINNER + c) * NSTATE;
    #pragma unroll
    for (int n = 0; n < NSTATE; ++n) h[n] = Hin[ho + n];

    __shared__ float sBC[CHUNK][2 * NSTATE];
    const short* dbc_mb = (const short*)dbc + (long)m * MROWS * 64 + (long)b * LSEQ * 64;
    const int t0 = chunk * CHUNK;
    for (int i = tid; i < CHUNK * 2 * NSTATE; i += 256) {
        int tt = i >> 5, j = i & 31;
        sBC[tt][j] = bf2f(dbc_mb[(long)(t0 + tt) * 64 + 32 + j]);
    }
    __syncthreads();

    const short* dp = (const short*)delta;
    const short* up = (const short*)xc;
    const short* zp = (const short*)zbuf;
    short* yp = (short*)ybuf;
    const long base = ((long)mb * LSEQ + t0) * DINNER + c;
    #pragma unroll 4
    for (int tt = 0; tt < CHUNK; ++tt) {
        const long idx = base + (long)tt * DINNER;
        const float d = bf2f(dp[idx]);
        const float u = bf2f(up[idx]);
        const float zv = bf2f(zp[idx]);
        const float du = d * u;
        float y = 0.f;
        #pragma unroll
        for (int n = 0; n < NSTATE; ++n) {
            float e = EXP2F(d * A2[n]);
            h[n] = e * h[n] + du * sBC[tt][n];
            y += h[n] * sBC[tt][16 + n];
        }
        y += u * Dsk;
        yp[idx] = f2bf(y * (zv * sigmoid_f(zv)));
    }
}

extern "C" void kernel_launch(void* const* d_in, const int* in_sizes, int n_in,
                              void* d_out, int out_size, void* d_ws, size_t ws_size,
                              hipStream_t stream)
{
    const float* v       = (const float*)d_in[0];
    const float* a       = (const float*)d_in[1];
    const float* t       = (const float*)d_in[2];
    const float* norm_w  = (const float*)d_in[3];
    const float* norm_b  = (const float*)d_in[4];
    const float* in_w    = (const float*)d_in[5];
    const float* conv_w  = (const float*)d_in[6];
    const float* conv_b  = (const float*)d_in[7];
    const float* xproj_w = (const float*)d_in[8];
    const float* dt_w    = (const float*)d_in[9];
    const float* dt_b    = (const float*)d_in[10];
    const float* A_log   = (const float*)d_in[11];
    const float* D_skip  = (const float*)d_in[12];
    const float* out_w   = (const float*)d_in[13];
    const float* couple_w= (const float*)d_in[14];
    const float* coef    = (const float*)d_in[15];
    float* out = (float*)d_out;

    typedef __hip_bfloat16 bf;
    float* x_in   = (float*)d_ws;                       // [3][4096][512] f32
    bf* xn_bf     = (bf*)(x_in + 6291456);              // [3][4096][512]
    bf* sec_bf    = xn_bf + 6291456;                    // [3][4096][512]
    bf* xcpre_bf  = sec_bf + 6291456;                   // [3][4096][1024]  (reused as ybuf)
    bf* z_bf      = xcpre_bf + 12582912;                // [3][4096][1024]
    bf* xc_bf     = z_bf + 12582912;                    // [3][4096][1024]
    bf* delta_bf  = xc_bf + 12582912;                   // [3][4096][1024]
    bf* dbc_bf    = delta_bf + 12582912;                // [3][4096][64]
    bf* cw_bf     = dbc_bf + 786432;                    // [3][512][512]
    bf* inw_bf    = cw_bf + 786432;                     // [3][2048][512]
    bf* xpw_bf    = inw_bf + 3145728;                   // [3][64][1024]
    bf* dtw_bf    = xpw_bf + 196608;                    // [3][1024][32]
    bf* outw_bf   = dtw_bf + 98304;                     // [3][512][1024]
    float* cwT    = (float*)(outw_bf + 1572864);        // [3][4][1024] f32
    float* Fbuf   = cwT + 12288;                        // [6][64][1024][16] = 6,291,456 f32
    bf* ybuf_bf   = xcpre_bf;                           // alias (xcpre dead after conv)

    float* Dbuf = out;                                  // [6][64][1024][16] — exactly out_size

    dim3 blk(256);

    // 0. conversions + conv-weight transpose + stack
    stack_vat_kernel<<<6144, blk, 0, stream>>>(v, a, t, x_in, sec_bf);
    cvt_all_kernel<<<(196608 + 786432 + 49152 + 24576 + 393216 + 255) / 256, blk, 0, stream>>>(
        couple_w, cw_bf, 196608, in_w, inw_bf, 786432, xproj_w, xpw_bf, 49152,
        dt_w, dtw_bf, 24576, out_w, outw_bf, 393216);
    conv_wt_kernel<<<48, blk, 0, stream>>>(conv_w, cwT);

    // 1. coupling: x_in += coef[z] * sec_bf @ cw^T
    gemm_bf16<4><<<dim3(4, 32, 3), blk, 0, stream>>>(
        (bf*)sec_bf, cw_bf, 512, 512, 512, 2097152L, 262144L,
        x_in, nullptr, 512, 2097152L, x_in, 2097152L, coef, 1, nullptr, 0L, 0);
    // 2. layernorm -> bf16
    ln_kernel<<<3*4096, blk, 0, stream>>>(x_in, xn_bf, norm_w, norm_b);
    // 3. in_proj halves -> bf16
    gemm_bf16<4><<<dim3(8, 32, 3), blk, 0, stream>>>(
        xn_bf, inw_bf, 512, 512, 512, 2097152L, 1048576L,
        nullptr, xcpre_bf, 1024, 4194304L, nullptr, 0L, nullptr, 0, nullptr, 0L, 0);
    gemm_bf16<4><<<dim3(8, 32, 3), blk, 0, stream>>>(
        xn_bf, inw_bf + 524288, 512, 512, 512, 2097152L, 1048576L,
        nullptr, z_bf, 1024, 4194304L, nullptr, 0L, nullptr, 0, nullptr, 0L, 0);
    // 4. conv + SiLU
    conv_silu_kernel<<<768, blk, 0, stream>>>(xcpre_bf, cwT, conv_b, xc_bf);
    // 5. x_proj -> dbc bf16
    gemm_bf16<2><<<dim3(1, 32, 3), blk, 0, stream>>>(
        xc_bf, xpw_bf, 1024, 1024, 1024, 4194304L, 65536L,
        nullptr, dbc_bf, 64, 262144L, nullptr, 0L, nullptr, 0, nullptr, 0L, 0);
    // 6. delta = softplus(dt @ dt_w^T + dt_b) -> bf16
    gemm_bf16<4><<<dim3(8, 32, 3), blk, 0, stream>>>(
        dbc_bf, dtw_bf, 32, 64, 32, 262144L, 32768L,
        nullptr, delta_bf, 1024, 4194304L, nullptr, 0L, nullptr, 0, dt_b, 1024L, 1);
    // 7. chunk-parallel scan (64 chunks of 32)
    scan_pass1_kernel<<<6*4*NCHUNK, blk, 0, stream>>>(delta_bf, xc_bf, dbc_bf, A_log, Fbuf, Dbuf);
    scan_pass2_kernel<<<(6*1024*16)/256, blk, 0, stream>>>(Fbuf, Dbuf);
    scan_pass3_kernel<<<6*4*NCHUNK, blk, 0, stream>>>(delta_bf, xc_bf, dbc_bf, z_bf,
                                                      A_log, D_skip, Fbuf, ybuf_bf);
    // 8. out_proj + residual -> d_out (f32)
    gemm_bf16<4><<<dim3(4, 32, 3), blk, 0, stream>>>(
        ybuf_bf, outw_bf, 1024, 1024, 1024, 4194304L, 524288L,
        out, nullptr, 512, 2097152L, x_in, 2097152L, nullptr, 0, nullptr, 0L, 0);
}

// Round 6
// 330.620 us; speedup vs baseline: 6.6537x; 1.0953x over previous
//
#include <hip/hip_runtime.h>
#include <hip/hip_bf16.h>

#define MODS 3
#define BSZ 2
#define LSEQ 2048
#define DMODEL 512
#define DINNER 1024
#define DTRANK 32
#define NSTATE 16
#define DCONV 4
#define MROWS (BSZ*LSEQ)   // 4096
#define NCHUNK 64
#define CHUNK 32           // LSEQ / NCHUNK

#define LOG2E 1.44269504088896f
#define LN2   0.69314718055995f

typedef __attribute__((ext_vector_type(8))) short short8v;
typedef __attribute__((ext_vector_type(4))) short short4v;
typedef __attribute__((ext_vector_type(2))) short short2v;
typedef __attribute__((ext_vector_type(4))) float f32x4;

#if __has_builtin(__builtin_amdgcn_exp2f)
#define EXP2F __builtin_amdgcn_exp2f
#else
#define EXP2F exp2f
#endif
#if __has_builtin(__builtin_amdgcn_rcpf)
#define RCPF __builtin_amdgcn_rcpf
#else
#define RCPF(x) (1.0f / (x))
#endif

__device__ __forceinline__ short f2bf(float x) {
    __hip_bfloat16 h = __float2bfloat16(x);
    return __builtin_bit_cast(short, h);
}
__device__ __forceinline__ float bf2f(short s) {
    return __uint_as_float(((unsigned)(unsigned short)s) << 16);
}
__device__ __forceinline__ void gl_lds16(const short* g, short* l) {
    __builtin_amdgcn_global_load_lds(
        (const __attribute__((address_space(1))) unsigned int*)g,
        (__attribute__((address_space(3))) unsigned int*)l, 16, 0, 0);
}
__device__ __forceinline__ float sigmoid_f(float x) {
    return RCPF(1.f + EXP2F(-x * LOG2E));
}

// ---------------- bf16 MFMA GEMM NT ----------------
template<int NJ>
__global__ __launch_bounds__(256) void gemm_bf16(
    const __hip_bfloat16* __restrict__ A_, const __hip_bfloat16* __restrict__ B_,
    int K, int lda, int ldb, long sA, long sB,
    float* __restrict__ Cf, __hip_bfloat16* __restrict__ Cb, int ldc, long sC,
    const float* __restrict__ res, long sRes,
    const float* __restrict__ coef_base, int coef_stride,
    const float* __restrict__ bias, long sBias, int act)
{
    constexpr int BN = NJ * 32;
    __shared__ alignas(16) short As[128 * 32];
    __shared__ alignas(16) short Bs[BN * 32];
    const int z = blockIdx.z;
    const int bm0 = blockIdx.y * 128;
    const int bn0 = blockIdx.x * BN;
    const short* Ag = (const short*)A_ + z * sA + (long)bm0 * lda;
    const short* Bg = (const short*)B_ + z * sB + (long)bn0 * ldb;
    const int tid = threadIdx.x;
    const int lane = tid & 63;
    const int w = tid >> 6;
    const int wr = w >> 1, wc = w & 1;
    const int lr = lane & 15, lk = (lane >> 4) * 8;
    const int arow = tid >> 2;
    const int aseg = (tid & 3) * 8;

    f32x4 acc[4][NJ];
    #pragma unroll
    for (int i = 0; i < 4; ++i)
        #pragma unroll
        for (int j = 0; j < NJ; ++j)
            acc[i][j] = (f32x4){0.f, 0.f, 0.f, 0.f};

    for (int k0 = 0; k0 < K; k0 += 32) {
        gl_lds16(Ag + (long)arow * lda + k0 + aseg, As + tid * 8);
        gl_lds16(Ag + (long)(64 + arow) * lda + k0 + aseg, As + 2048 + tid * 8);
        gl_lds16(Bg + (long)arow * ldb + k0 + aseg, Bs + tid * 8);
        if constexpr (NJ == 4)
            gl_lds16(Bg + (long)(64 + arow) * ldb + k0 + aseg, Bs + 2048 + tid * 8);
        __syncthreads();
        short8v af[4], bfr[NJ];
        #pragma unroll
        for (int i = 0; i < 4; ++i)
            af[i] = *(const short8v*)&As[(wr * 64 + i * 16 + lr) * 32 + lk];
        #pragma unroll
        for (int j = 0; j < NJ; ++j)
            bfr[j] = *(const short8v*)&Bs[(wc * NJ * 16 + j * 16 + lr) * 32 + lk];
        #pragma unroll
        for (int i = 0; i < 4; ++i)
            #pragma unroll
            for (int j = 0; j < NJ; ++j)
                acc[i][j] = __builtin_amdgcn_mfma_f32_16x16x32_bf16(af[i], bfr[j], acc[i][j], 0, 0, 0);
        __syncthreads();
    }

    const float alpha = coef_base ? coef_base[z * coef_stride] : 1.0f;
    const float* resz = res ? res + z * sRes : nullptr;
    const float* biasz = bias ? bias + z * sBias : nullptr;
    float* Cfz = Cf ? Cf + z * sC : nullptr;
    __hip_bfloat16* Cbz = Cb ? Cb + z * sC : nullptr;
    #pragma unroll
    for (int i = 0; i < 4; ++i) {
        #pragma unroll
        for (int r = 0; r < 4; ++r) {
            const int row = bm0 + wr * 64 + i * 16 + (lane >> 4) * 4 + r;
            #pragma unroll
            for (int j = 0; j < NJ; ++j) {
                const int col = bn0 + wc * NJ * 16 + j * 16 + lr;
                float val = acc[i][j][r];
                if (biasz) val += biasz[col];
                if (act == 1)
                    val = (val > 20.f) ? val : LN2 * __log2f(1.f + EXP2F(val * LOG2E));
                val *= alpha;
                if (resz) val += resz[(long)row * ldc + col];
                if (Cfz) Cfz[(long)row * ldc + col] = val;
                else     Cbz[(long)row * ldc + col] = __float2bfloat16(val);
            }
        }
    }
}

// ---------------- stack: x_in = [v;a;t] f32, sec_bf = [a;t;v] bf16 ----------------
__global__ __launch_bounds__(256) void stack_vat_kernel(
    const float* __restrict__ v, const float* __restrict__ a, const float* __restrict__ t,
    float* __restrict__ x_in, __hip_bfloat16* __restrict__ sec_bf)
{
    const long idx = (long)blockIdx.x * 256 + threadIdx.x;
    const int m = (int)(idx >> 19);
    const long off = idx & 524287;
    const float* prim = (m == 0) ? v : (m == 1) ? a : t;
    const float* sec  = (m == 0) ? a : (m == 1) ? t : v;
    float4 pv = ((const float4*)prim)[off];
    float4 sv = ((const float4*)sec)[off];
    ((float4*)x_in)[idx] = pv;
    short4v s;
    s.x = f2bf(sv.x); s.y = f2bf(sv.y); s.z = f2bf(sv.z); s.w = f2bf(sv.w);
    ((short4v*)sec_bf)[idx] = s;
}

// ---------------- fused weight conversions: 5 segments f32 -> bf16 ----------------
__global__ __launch_bounds__(256) void cvt_all_kernel(
    const float* __restrict__ s0, __hip_bfloat16* __restrict__ d0, int n0,
    const float* __restrict__ s1, __hip_bfloat16* __restrict__ d1, int n1,
    const float* __restrict__ s2, __hip_bfloat16* __restrict__ d2, int n2,
    const float* __restrict__ s3, __hip_bfloat16* __restrict__ d3, int n3,
    const float* __restrict__ s4, __hip_bfloat16* __restrict__ d4, int n4)
{
    int idx = blockIdx.x * 256 + threadIdx.x;
    const float* s; __hip_bfloat16* d; int off = idx;
    if      (off < n0)                  { s = s0; d = d0; }
    else if ((off -= n0) < n1)          { s = s1; d = d1; }
    else if ((off -= n1) < n2)          { s = s2; d = d2; }
    else if ((off -= n2) < n3)          { s = s3; d = d3; }
    else if ((off -= n3) < n4)          { s = s4; d = d4; }
    else return;
    float4 vv = ((const float4*)s)[off];
    short4v o;
    o.x = f2bf(vv.x); o.y = f2bf(vv.y); o.z = f2bf(vv.z); o.w = f2bf(vv.w);
    ((short4v*)d)[off] = o;
}

// ---------------- small prep: conv-weight transpose + A2T ----------------
// cwT[m][k][c] = conv_w[m][c][k];  A2T[m][n][c] = -exp(A_log[m][c][n]) * log2e
__global__ __launch_bounds__(256) void small_prep_kernel(const float* __restrict__ cw,
    float* __restrict__ cwT, const float* __restrict__ A_log, float* __restrict__ A2T)
{
    const int idx = blockIdx.x * 256 + threadIdx.x;
    if (idx < MODS * DINNER * DCONV) {
        const int k = idx & 3;
        const int c = (idx >> 2) & 1023;
        const int m = idx >> 12;
        cwT[(m * DCONV + k) * DINNER + c] = cw[idx];
    } else if (idx < MODS * DINNER * DCONV + MODS * NSTATE * DINNER) {
        const int j = idx - MODS * DINNER * DCONV;
        const int c = j & 1023;
        const int n = (j >> 10) & 15;
        const int m = j >> 14;
        A2T[j] = -EXP2F(A_log[((long)m * DINNER + c) * NSTATE + n] * LOG2E) * LOG2E;
    }
}

// ---------------- LayerNorm: f32 in -> bf16 out ----------------
__global__ __launch_bounds__(256) void ln_kernel(const float* __restrict__ x, __hip_bfloat16* __restrict__ xn,
                                                 const float* __restrict__ nw, const float* __restrict__ nb)
{
    const int row = blockIdx.x;
    const int m = row >> 12;
    const int tid = threadIdx.x;
    const float2 v = *reinterpret_cast<const float2*>(x + (long)row * DMODEL + tid * 2);
    float s = v.x + v.y;
    float sq = v.x * v.x + v.y * v.y;
    #pragma unroll
    for (int off = 32; off > 0; off >>= 1) {
        s  += __shfl_down(s, off);
        sq += __shfl_down(sq, off);
    }
    __shared__ float ws_s[4], ws_q[4];
    const int wid = tid >> 6, lane = tid & 63;
    if (lane == 0) { ws_s[wid] = s; ws_q[wid] = sq; }
    __syncthreads();
    if (tid == 0) {
        float ts = ws_s[0] + ws_s[1] + ws_s[2] + ws_s[3];
        float tq = ws_q[0] + ws_q[1] + ws_q[2] + ws_q[3];
        float mu = ts / DMODEL;
        float var = tq / DMODEL - mu * mu;
        ws_s[0] = mu;
        ws_q[0] = rsqrtf(var + 1e-5f);
    }
    __syncthreads();
    const float mu = ws_s[0], rstd = ws_q[0];
    const int e0 = tid * 2;
    float2 w  = *reinterpret_cast<const float2*>(nw + m * DMODEL + e0);
    float2 bb = *reinterpret_cast<const float2*>(nb + m * DMODEL + e0);
    short2v o;
    o.x = f2bf((v.x - mu) * rstd * w.x + bb.x);
    o.y = f2bf((v.y - mu) * rstd * w.y + bb.y);
    *reinterpret_cast<short2v*>((short*)xn + (long)row * DMODEL + e0) = o;
}

// ---------------- depthwise causal conv(4) + SiLU ----------------
// input: xz [mb][t][2048] cols 0..1023; output: xc [mb][t][1024]
__global__ __launch_bounds__(256) void conv_silu_kernel(const __hip_bfloat16* __restrict__ xz,
    const float* __restrict__ cwT, const float* __restrict__ cb, __hip_bfloat16* __restrict__ xc)
{
    const int idx = blockIdx.x * 256 + threadIdx.x;   // < 6*256*128 = 196608
    const int c8 = idx & 127;
    const int lt = (idx >> 7) & 255;
    const int mb = idx >> 15;
    const int m  = mb >> 1;
    const int c0 = c8 * 8;
    const int l0 = lt * 8;

    float4 wlo[DCONV], whi[DCONV];
    #pragma unroll
    for (int k = 0; k < DCONV; ++k) {
        wlo[k] = *(const float4*)&cwT[(m * DCONV + k) * DINNER + c0];
        whi[k] = *(const float4*)&cwT[(m * DCONV + k) * DINNER + c0 + 4];
    }
    const float4 blo = *(const float4*)&cb[m * DINNER + c0];
    const float4 bhi = *(const float4*)&cb[m * DINNER + c0 + 4];

    const short* base = (const short*)xz + (long)mb * LSEQ * 2048 + c0;
    short* obase = (short*)xc + (long)mb * LSEQ * DINNER + c0;

    short8v r0 = {}, r1 = {}, r2 = {};
    if (l0 - 3 >= 0) r0 = *(const short8v*)(base + (long)(l0 - 3) * 2048);
    if (l0 - 2 >= 0) r1 = *(const short8v*)(base + (long)(l0 - 2) * 2048);
    if (l0 - 1 >= 0) r2 = *(const short8v*)(base + (long)(l0 - 1) * 2048);

    #pragma unroll
    for (int i = 0; i < 8; ++i) {
        const short8v cur = *(const short8v*)(base + (long)(l0 + i) * 2048);
        float acc[8];
        #pragma unroll
        for (int j = 0; j < 4; ++j) {
            acc[j]     = ((const float*)&blo)[j];
            acc[4 + j] = ((const float*)&bhi)[j];
        }
        #pragma unroll
        for (int j = 0; j < 8; ++j) {
            const float w0 = (j < 4) ? ((const float*)&wlo[0])[j] : ((const float*)&whi[0])[j - 4];
            const float w1 = (j < 4) ? ((const float*)&wlo[1])[j] : ((const float*)&whi[1])[j - 4];
            const float w2 = (j < 4) ? ((const float*)&wlo[2])[j] : ((const float*)&whi[2])[j - 4];
            const float w3 = (j < 4) ? ((const float*)&wlo[3])[j] : ((const float*)&whi[3])[j - 4];
            acc[j] += w0 * bf2f(r0[j]) + w1 * bf2f(r1[j]) + w2 * bf2f(r2[j]) + w3 * bf2f(cur[j]);
        }
        short8v o;
        #pragma unroll
        for (int j = 0; j < 8; ++j)
            o[j] = f2bf(acc[j] * sigmoid_f(acc[j]));
        *(short8v*)(obase + (long)(l0 + i) * DINNER) = o;
        r0 = r1; r1 = r2; r2 = cur;
    }
}

// ---------------- chunk-parallel selective scan (bf16 activations) ----------------
// F/D layout: [mb][chunk][n][c] — all accesses lane-coalesced over c.
__global__ __launch_bounds__(256) void scan_pass1_kernel(
    const __hip_bfloat16* __restrict__ delta, const __hip_bfloat16* __restrict__ xc,
    const __hip_bfloat16* __restrict__ dbc, const float* __restrict__ A2T,
    float* __restrict__ Fbuf, float* __restrict__ Dbuf)
{
    const int bx = blockIdx.x;             // mb(6) x cg(4) x chunk(64)
    const int chunk = bx & (NCHUNK - 1);
    const int cg = (bx >> 6) & 3;
    const int mb = bx >> 8;
    const int m = mb >> 1, b = mb & 1;
    const int tid = threadIdx.x;
    const int c = cg * 256 + tid;

    float A2[NSTATE];
    #pragma unroll
    for (int n = 0; n < NSTATE; ++n)
        A2[n] = A2T[((long)m * NSTATE + n) * DINNER + c];
    float h[NSTATE] = {};
    float sum_d = 0.f;

    __shared__ float sB[CHUNK][NSTATE];
    const short* dbc_mb = (const short*)dbc + (long)m * MROWS * 64 + (long)b * LSEQ * 64;
    const int t0 = chunk * CHUNK;
    for (int i = tid; i < CHUNK * NSTATE; i += 256) {
        int tt = i >> 4, j = i & 15;
        sB[tt][j] = bf2f(dbc_mb[(long)(t0 + tt) * 64 + 32 + j]);
    }
    __syncthreads();

    const short* dp = (const short*)delta;
    const short* up = (const short*)xc;
    const long base = ((long)mb * LSEQ + t0) * DINNER + c;
    #pragma unroll 4
    for (int tt = 0; tt < CHUNK; ++tt) {
        const float d = bf2f(dp[base + (long)tt * DINNER]);
        const float u = bf2f(up[base + (long)tt * DINNER]);
        const float du = d * u;
        sum_d += d;
        #pragma unroll
        for (int n = 0; n < NSTATE; ++n) {
            float e = EXP2F(d * A2[n]);
            h[n] = e * h[n] + du * sB[tt][n];
        }
    }
    const long ob = ((long)mb * NCHUNK + chunk) * (NSTATE * DINNER) + c;
    #pragma unroll
    for (int n = 0; n < NSTATE; ++n) {
        Fbuf[ob + n * DINNER] = h[n];
        Dbuf[ob + n * DINNER] = EXP2F(sum_d * A2[n]);
    }
}

__global__ __launch_bounds__(256) void scan_pass2_kernel(float* __restrict__ Fbuf,
                                                         const float* __restrict__ Dbuf)
{
    const long idx = (long)blockIdx.x * 256 + threadIdx.x;  // < 6*16*1024
    const int mb = (int)(idx >> 14);
    const int cn = (int)(idx & 16383);        // n*1024 + c
    float run = 0.f;
    for (int k = 0; k < NCHUNK; ++k) {
        const long o = ((long)(mb * NCHUNK + k) << 14) + cn;
        const float f = Fbuf[o];
        const float p = Dbuf[o];
        Fbuf[o] = run;
        run = p * run + f;
    }
}

// z read from xz cols 1024..2047; y written into xz cols 0..1023 (dead after conv)
__global__ __launch_bounds__(256) void scan_pass3_kernel(
    const __hip_bfloat16* __restrict__ delta, const __hip_bfloat16* __restrict__ xc,
    const __hip_bfloat16* __restrict__ dbc, __hip_bfloat16* __restrict__ xz,
    const float* __restrict__ A2T, const float* __restrict__ D_skip,
    const float* __restrict__ Hin)
{
    const int bx = blockIdx.x;
    const int chunk = bx & (NCHUNK - 1);
    const int cg = (bx >> 6) & 3;
    const int mb = bx >> 8;
    const int m = mb >> 1, b = mb & 1;
    const int tid = threadIdx.x;
    const int c = cg * 256 + tid;

    float A2[NSTATE];
    #pragma unroll
    for (int n = 0; n < NSTATE; ++n)
        A2[n] = A2T[((long)m * NSTATE + n) * DINNER + c];
    const float Dsk = D_skip[m * DINNER + c];

    float h[NSTATE];
    const long ho = ((long)mb * NCHUNK + chunk) * (NSTATE * DINNER) + c;
    #pragma unroll
    for (int n = 0; n < NSTATE; ++n) h[n] = Hin[ho + n * DINNER];

    __shared__ float sBC[CHUNK][2 * NSTATE];
    const short* dbc_mb = (const short*)dbc + (long)m * MROWS * 64 + (long)b * LSEQ * 64;
    const int t0 = chunk * CHUNK;
    for (int i = tid; i < CHUNK * 2 * NSTATE; i += 256) {
        int tt = i >> 5, j = i & 31;
        sBC[tt][j] = bf2f(dbc_mb[(long)(t0 + tt) * 64 + 32 + j]);
    }
    __syncthreads();

    const short* dp = (const short*)delta;
    const short* up = (const short*)xc;
    short* xzp = (short*)xz;
    const long base = ((long)mb * LSEQ + t0) * DINNER + c;
    const long xbase = ((long)mb * LSEQ + t0) * 2048 + c;
    #pragma unroll 4
    for (int tt = 0; tt < CHUNK; ++tt) {
        const long idx = base + (long)tt * DINNER;
        const long xi  = xbase + (long)tt * 2048;
        const float d = bf2f(dp[idx]);
        const float u = bf2f(up[idx]);
        const float zv = bf2f(xzp[xi + 1024]);
        const float du = d * u;
        float y = 0.f;
        #pragma unroll
        for (int n = 0; n < NSTATE; ++n) {
            float e = EXP2F(d * A2[n]);
            h[n] = e * h[n] + du * sBC[tt][n];
            y += h[n] * sBC[tt][16 + n];
        }
        y += u * Dsk;
        xzp[xi] = f2bf(y * (zv * sigmoid_f(zv)));
    }
}

extern "C" void kernel_launch(void* const* d_in, const int* in_sizes, int n_in,
                              void* d_out, int out_size, void* d_ws, size_t ws_size,
                              hipStream_t stream)
{
    const float* v       = (const float*)d_in[0];
    const float* a       = (const float*)d_in[1];
    const float* t       = (const float*)d_in[2];
    const float* norm_w  = (const float*)d_in[3];
    const float* norm_b  = (const float*)d_in[4];
    const float* in_w    = (const float*)d_in[5];
    const float* conv_w  = (const float*)d_in[6];
    const float* conv_b  = (const float*)d_in[7];
    const float* xproj_w = (const float*)d_in[8];
    const float* dt_w    = (const float*)d_in[9];
    const float* dt_b    = (const float*)d_in[10];
    const float* A_log   = (const float*)d_in[11];
    const float* D_skip  = (const float*)d_in[12];
    const float* out_w   = (const float*)d_in[13];
    const float* couple_w= (const float*)d_in[14];
    const float* coef    = (const float*)d_in[15];
    float* out = (float*)d_out;

    typedef __hip_bfloat16 bf;
    float* x_in   = (float*)d_ws;                       // [3][4096][512] f32
    bf* xn_bf     = (bf*)(x_in + 6291456);              // [3][4096][512]
    bf* sec_bf    = xn_bf + 6291456;                    // [3][4096][512]
    bf* xz_bf     = sec_bf + 6291456;                   // [3][4096][2048]  (xc-pre | z; later y | z)
    bf* xc_bf     = xz_bf + 25165824;                   // [3][4096][1024]
    bf* delta_bf  = xc_bf + 12582912;                   // [3][4096][1024]
    bf* dbc_bf    = delta_bf + 12582912;                // [3][4096][64]
    bf* cw_bf     = dbc_bf + 786432;                    // [3][512][512]
    bf* inw_bf    = cw_bf + 786432;                     // [3][2048][512]
    bf* xpw_bf    = inw_bf + 3145728;                   // [3][64][1024]
    bf* dtw_bf    = xpw_bf + 196608;                    // [3][1024][32]
    bf* outw_bf   = dtw_bf + 98304;                     // [3][512][1024]
    float* cwT    = (float*)(outw_bf + 1572864);        // [3][4][1024] f32
    float* A2T    = cwT + 12288;                        // [3][16][1024] f32
    float* Fbuf   = A2T + 49152;                        // [6][64][16][1024] f32

    float* Dbuf = out;                                  // [6][64][16][1024] — exactly out_size

    dim3 blk(256);

    // 0. prep: stack + weight conversions + conv-wT/A2T
    stack_vat_kernel<<<6144, blk, 0, stream>>>(v, a, t, x_in, sec_bf);
    cvt_all_kernel<<<(196608 + 786432 + 49152 + 24576 + 393216 + 255) / 256, blk, 0, stream>>>(
        couple_w, cw_bf, 196608, in_w, inw_bf, 786432, xproj_w, xpw_bf, 49152,
        dt_w, dtw_bf, 24576, out_w, outw_bf, 393216);
    small_prep_kernel<<<(12288 + 49152 + 255) / 256, blk, 0, stream>>>(conv_w, cwT, A_log, A2T);

    // 1. coupling: x_in += coef[z] * sec_bf @ cw^T
    gemm_bf16<4><<<dim3(4, 32, 3), blk, 0, stream>>>(
        (bf*)sec_bf, cw_bf, 512, 512, 512, 2097152L, 262144L,
        x_in, nullptr, 512, 2097152L, x_in, 2097152L, coef, 1, nullptr, 0L, 0);
    // 2. layernorm -> bf16
    ln_kernel<<<3*4096, blk, 0, stream>>>(x_in, xn_bf, norm_w, norm_b);
    // 3. in_proj (both halves, N=2048) -> xz
    gemm_bf16<4><<<dim3(16, 32, 3), blk, 0, stream>>>(
        xn_bf, inw_bf, 512, 512, 512, 2097152L, 1048576L,
        nullptr, xz_bf, 2048, 8388608L, nullptr, 0L, nullptr, 0, nullptr, 0L, 0);
    // 4. conv + SiLU (reads xz cols 0..1023)
    conv_silu_kernel<<<768, blk, 0, stream>>>(xz_bf, cwT, conv_b, xc_bf);
    // 5. x_proj -> dbc bf16
    gemm_bf16<2><<<dim3(1, 32, 3), blk, 0, stream>>>(
        xc_bf, xpw_bf, 1024, 1024, 1024, 4194304L, 65536L,
        nullptr, dbc_bf, 64, 262144L, nullptr, 0L, nullptr, 0, nullptr, 0L, 0);
    // 6. delta = softplus(dt @ dt_w^T + dt_b) -> bf16
    gemm_bf16<4><<<dim3(8, 32, 3), blk, 0, stream>>>(
        dbc_bf, dtw_bf, 32, 64, 32, 262144L, 32768L,
        nullptr, delta_bf, 1024, 4194304L, nullptr, 0L, nullptr, 0, dt_b, 1024L, 1);
    // 7. chunk-parallel scan
    scan_pass1_kernel<<<6*4*NCHUNK, blk, 0, stream>>>(delta_bf, xc_bf, dbc_bf, A2T, Fbuf, Dbuf);
    scan_pass2_kernel<<<(6*1024*16)/256, blk, 0, stream>>>(Fbuf, Dbuf);
    scan_pass3_kernel<<<6*4*NCHUNK, blk, 0, stream>>>(delta_bf, xc_bf, dbc_bf, xz_bf,
                                                      A2T, D_skip, Fbuf);
    // 8. out_proj + residual -> d_out (f32); A = y in xz cols 0..1023, lda 2048
    gemm_bf16<4><<<dim3(4, 32, 3), blk, 0, stream>>>(
        xz_bf, outw_bf, 1024, 2048, 1024, 8388608L, 524288L,
        out, nullptr, 512, 2097152L, x_in, 2097152L, nullptr, 0, nullptr, 0L, 0);
}

// Round 7
// 322.620 us; speedup vs baseline: 6.8186x; 1.0248x over previous
//
#include <hip/hip_runtime.h>
#include <hip/hip_bf16.h>

#define MODS 3
#define BSZ 2
#define LSEQ 2048
#define DMODEL 512
#define DINNER 1024
#define DTRANK 32
#define NSTATE 16
#define DCONV 4
#define MROWS (BSZ*LSEQ)   // 4096
#define NCHUNK 64
#define CHUNK 32           // LSEQ / NCHUNK

#define LOG2E 1.44269504088896f
#define LN2   0.69314718055995f

typedef __attribute__((ext_vector_type(8))) short short8v;
typedef __attribute__((ext_vector_type(4))) short short4v;
typedef __attribute__((ext_vector_type(2))) short short2v;
typedef __attribute__((ext_vector_type(4))) float f32x4;

#if __has_builtin(__builtin_amdgcn_exp2f)
#define EXP2F __builtin_amdgcn_exp2f
#else
#define EXP2F exp2f
#endif
#if __has_builtin(__builtin_amdgcn_rcpf)
#define RCPF __builtin_amdgcn_rcpf
#else
#define RCPF(x) (1.0f / (x))
#endif

__device__ __forceinline__ short f2bf(float x) {
    __hip_bfloat16 h = __float2bfloat16(x);
    return __builtin_bit_cast(short, h);
}
__device__ __forceinline__ float bf2f(short s) {
    return __uint_as_float(((unsigned)(unsigned short)s) << 16);
}
__device__ __forceinline__ void gl_lds16(const short* g, short* l) {
    __builtin_amdgcn_global_load_lds(
        (const __attribute__((address_space(1))) unsigned int*)g,
        (__attribute__((address_space(3))) unsigned int*)l, 16, 0, 0);
}
__device__ __forceinline__ float sigmoid_f(float x) {
    return RCPF(1.f + EXP2F(-x * LOG2E));
}

// ---------------- bf16 MFMA GEMM NT, XOR-swizzled LDS ----------------
// C[z] = res[z] + coef[z] * act(A[z] @ B[z]^T + bias[z])
// Tile 128 x (NJ*32). BK = 64 (K%64==0) or 32. Swizzle: LDS holds
// tile[row][slot^f(row)] = global[row][slot] (16B slots); staging pre-swizzles
// the GLOBAL source (per-lane addr) so global_load_lds dest stays linear,
// reads apply the same XOR -> conflict-free ds_read_b128.
template<int NJ, int BK>
__global__ __launch_bounds__(256) void gemm_bf16(
    const __hip_bfloat16* __restrict__ A_, const __hip_bfloat16* __restrict__ B_,
    int K, int lda, int ldb, long sA, long sB,
    float* __restrict__ Cf, __hip_bfloat16* __restrict__ Cb, int ldc, long sC,
    const float* __restrict__ res, long sRes,
    const float* __restrict__ coef_base, int coef_stride,
    const float* __restrict__ bias, long sBias, int act)
{
    constexpr int BN = NJ * 32;
    __shared__ alignas(16) short As[128 * BK];
    __shared__ alignas(16) short Bs[BN * BK];
    const int z = blockIdx.z;
    const int bm0 = blockIdx.y * 128;
    const int bn0 = blockIdx.x * BN;
    const short* Ag = (const short*)A_ + z * sA + (long)bm0 * lda;
    const short* Bg = (const short*)B_ + z * sB + (long)bn0 * ldb;
    const int tid = threadIdx.x;
    const int lane = tid & 63;
    const int w = tid >> 6;
    const int wr = w >> 1, wc = w & 1;
    const int lr = lane & 15;
    const int sidx = lane >> 4;           // 16B slot group within K=32

    // staging decomposition (per gl_lds instr: 256 lanes x 16B = 2048 elems)
    int srow, sgcol;                      // local row, swizzled global elem col
    if constexpr (BK == 64) {
        srow = tid >> 3;                                  // 0..31
        sgcol = ((tid & 7) ^ (srow & 7)) * 8;
    } else {
        srow = tid >> 2;                                  // 0..63
        sgcol = ((tid & 3) ^ ((srow >> 1) & 3)) * 8;
    }
    // read-side swizzled slot base (element offset into LDS row)
    const int fA = (BK == 64) ? (lr & 7) : ((lr >> 1) & 3);

    f32x4 acc[4][NJ];
    #pragma unroll
    for (int i = 0; i < 4; ++i)
        #pragma unroll
        for (int j = 0; j < NJ; ++j)
            acc[i][j] = (f32x4){0.f, 0.f, 0.f, 0.f};

    constexpr int AINSTR = 128 * BK / 2048;
    constexpr int BINSTR = BN * BK / 2048;
    constexpr int RPI = 2048 / BK;        // rows per instr

    for (int k0 = 0; k0 < K; k0 += BK) {
        #pragma unroll
        for (int i = 0; i < AINSTR; ++i)
            gl_lds16(Ag + (long)(i * RPI + srow) * lda + k0 + sgcol, As + i * 2048 + tid * 8);
        #pragma unroll
        for (int i = 0; i < BINSTR; ++i)
            gl_lds16(Bg + (long)(i * RPI + srow) * ldb + k0 + sgcol, Bs + i * 2048 + tid * 8);
        __syncthreads();
        #pragma unroll
        for (int kh = 0; kh < BK / 32; ++kh) {
            const int sl = ((kh * 4 + sidx) ^ fA) * 8;
            short8v af[4], bfr[NJ];
            #pragma unroll
            for (int i = 0; i < 4; ++i)
                af[i] = *(const short8v*)&As[(wr * 64 + i * 16 + lr) * BK + sl];
            #pragma unroll
            for (int j = 0; j < NJ; ++j)
                bfr[j] = *(const short8v*)&Bs[(wc * NJ * 16 + j * 16 + lr) * BK + sl];
            #pragma unroll
            for (int i = 0; i < 4; ++i)
                #pragma unroll
                for (int j = 0; j < NJ; ++j)
                    acc[i][j] = __builtin_amdgcn_mfma_f32_16x16x32_bf16(af[i], bfr[j], acc[i][j], 0, 0, 0);
        }
        __syncthreads();
    }

    const float alpha = coef_base ? coef_base[z * coef_stride] : 1.0f;
    const float* resz = res ? res + z * sRes : nullptr;
    const float* biasz = bias ? bias + z * sBias : nullptr;
    float* Cfz = Cf ? Cf + z * sC : nullptr;
    __hip_bfloat16* Cbz = Cb ? Cb + z * sC : nullptr;
    #pragma unroll
    for (int i = 0; i < 4; ++i) {
        #pragma unroll
        for (int r = 0; r < 4; ++r) {
            const int row = bm0 + wr * 64 + i * 16 + (lane >> 4) * 4 + r;
            #pragma unroll
            for (int j = 0; j < NJ; ++j) {
                const int col = bn0 + wc * NJ * 16 + j * 16 + lr;
                float val = acc[i][j][r];
                if (biasz) val += biasz[col];
                if (act == 1)
                    val = (val > 20.f) ? val : LN2 * __log2f(1.f + EXP2F(val * LOG2E));
                val *= alpha;
                if (resz) val += resz[(long)row * ldc + col];
                if (Cfz) Cfz[(long)row * ldc + col] = val;
                else     Cbz[(long)row * ldc + col] = __float2bfloat16(val);
            }
        }
    }
}

// ---------------- stack: x_in = [v;a;t] f32, sec_bf = [a;t;v] bf16 ----------------
__global__ __launch_bounds__(256) void stack_vat_kernel(
    const float* __restrict__ v, const float* __restrict__ a, const float* __restrict__ t,
    float* __restrict__ x_in, __hip_bfloat16* __restrict__ sec_bf)
{
    const long idx = (long)blockIdx.x * 256 + threadIdx.x;
    const int m = (int)(idx >> 19);
    const long off = idx & 524287;
    const float* prim = (m == 0) ? v : (m == 1) ? a : t;
    const float* sec  = (m == 0) ? a : (m == 1) ? t : v;
    float4 pv = ((const float4*)prim)[off];
    float4 sv = ((const float4*)sec)[off];
    ((float4*)x_in)[idx] = pv;
    short4v s;
    s.x = f2bf(sv.x); s.y = f2bf(sv.y); s.z = f2bf(sv.z); s.w = f2bf(sv.w);
    ((short4v*)sec_bf)[idx] = s;
}

// ---------------- fused weight conversions: 5 segments f32 -> bf16 ----------------
__global__ __launch_bounds__(256) void cvt_all_kernel(
    const float* __restrict__ s0, __hip_bfloat16* __restrict__ d0, int n0,
    const float* __restrict__ s1, __hip_bfloat16* __restrict__ d1, int n1,
    const float* __restrict__ s2, __hip_bfloat16* __restrict__ d2, int n2,
    const float* __restrict__ s3, __hip_bfloat16* __restrict__ d3, int n3,
    const float* __restrict__ s4, __hip_bfloat16* __restrict__ d4, int n4)
{
    int idx = blockIdx.x * 256 + threadIdx.x;
    const float* s; __hip_bfloat16* d; int off = idx;
    if      (off < n0)                  { s = s0; d = d0; }
    else if ((off -= n0) < n1)          { s = s1; d = d1; }
    else if ((off -= n1) < n2)          { s = s2; d = d2; }
    else if ((off -= n2) < n3)          { s = s3; d = d3; }
    else if ((off -= n3) < n4)          { s = s4; d = d4; }
    else return;
    float4 vv = ((const float4*)s)[off];
    short4v o;
    o.x = f2bf(vv.x); o.y = f2bf(vv.y); o.z = f2bf(vv.z); o.w = f2bf(vv.w);
    ((short4v*)d)[off] = o;
}

// ---------------- small prep: conv-weight transpose + A2T ----------------
__global__ __launch_bounds__(256) void small_prep_kernel(const float* __restrict__ cw,
    float* __restrict__ cwT, const float* __restrict__ A_log, float* __restrict__ A2T)
{
    const int idx = blockIdx.x * 256 + threadIdx.x;
    if (idx < MODS * DINNER * DCONV) {
        const int k = idx & 3;
        const int c = (idx >> 2) & 1023;
        const int m = idx >> 12;
        cwT[(m * DCONV + k) * DINNER + c] = cw[idx];
    } else if (idx < MODS * DINNER * DCONV + MODS * NSTATE * DINNER) {
        const int j = idx - MODS * DINNER * DCONV;
        const int c = j & 1023;
        const int n = (j >> 10) & 15;
        const int m = j >> 14;
        A2T[j] = -EXP2F(A_log[((long)m * DINNER + c) * NSTATE + n] * LOG2E) * LOG2E;
    }
}

// ---------------- LayerNorm: f32 in -> bf16 out ----------------
__global__ __launch_bounds__(256) void ln_kernel(const float* __restrict__ x, __hip_bfloat16* __restrict__ xn,
                                                 const float* __restrict__ nw, const float* __restrict__ nb)
{
    const int row = blockIdx.x;
    const int m = row >> 12;
    const int tid = threadIdx.x;
    const float2 v = *reinterpret_cast<const float2*>(x + (long)row * DMODEL + tid * 2);
    float s = v.x + v.y;
    float sq = v.x * v.x + v.y * v.y;
    #pragma unroll
    for (int off = 32; off > 0; off >>= 1) {
        s  += __shfl_down(s, off);
        sq += __shfl_down(sq, off);
    }
    __shared__ float ws_s[4], ws_q[4];
    const int wid = tid >> 6, lane = tid & 63;
    if (lane == 0) { ws_s[wid] = s; ws_q[wid] = sq; }
    __syncthreads();
    if (tid == 0) {
        float ts = ws_s[0] + ws_s[1] + ws_s[2] + ws_s[3];
        float tq = ws_q[0] + ws_q[1] + ws_q[2] + ws_q[3];
        float mu = ts / DMODEL;
        float var = tq / DMODEL - mu * mu;
        ws_s[0] = mu;
        ws_q[0] = rsqrtf(var + 1e-5f);
    }
    __syncthreads();
    const float mu = ws_s[0], rstd = ws_q[0];
    const int e0 = tid * 2;
    float2 w  = *reinterpret_cast<const float2*>(nw + m * DMODEL + e0);
    float2 bb = *reinterpret_cast<const float2*>(nb + m * DMODEL + e0);
    short2v o;
    o.x = f2bf((v.x - mu) * rstd * w.x + bb.x);
    o.y = f2bf((v.y - mu) * rstd * w.y + bb.y);
    *reinterpret_cast<short2v*>((short*)xn + (long)row * DMODEL + e0) = o;
}

// ---------------- depthwise causal conv(4) + SiLU ----------------
__global__ __launch_bounds__(256) void conv_silu_kernel(const __hip_bfloat16* __restrict__ xz,
    const float* __restrict__ cwT, const float* __restrict__ cb, __hip_bfloat16* __restrict__ xc)
{
    const int idx = blockIdx.x * 256 + threadIdx.x;   // < 6*256*128 = 196608
    const int c8 = idx & 127;
    const int lt = (idx >> 7) & 255;
    const int mb = idx >> 15;
    const int m  = mb >> 1;
    const int c0 = c8 * 8;
    const int l0 = lt * 8;

    float4 wlo[DCONV], whi[DCONV];
    #pragma unroll
    for (int k = 0; k < DCONV; ++k) {
        wlo[k] = *(const float4*)&cwT[(m * DCONV + k) * DINNER + c0];
        whi[k] = *(const float4*)&cwT[(m * DCONV + k) * DINNER + c0 + 4];
    }
    const float4 blo = *(const float4*)&cb[m * DINNER + c0];
    const float4 bhi = *(const float4*)&cb[m * DINNER + c0 + 4];

    const short* base = (const short*)xz + (long)mb * LSEQ * 2048 + c0;
    short* obase = (short*)xc + (long)mb * LSEQ * DINNER + c0;

    short8v r0 = {}, r1 = {}, r2 = {};
    if (l0 - 3 >= 0) r0 = *(const short8v*)(base + (long)(l0 - 3) * 2048);
    if (l0 - 2 >= 0) r1 = *(const short8v*)(base + (long)(l0 - 2) * 2048);
    if (l0 - 1 >= 0) r2 = *(const short8v*)(base + (long)(l0 - 1) * 2048);

    #pragma unroll
    for (int i = 0; i < 8; ++i) {
        const short8v cur = *(const short8v*)(base + (long)(l0 + i) * 2048);
        float acc[8];
        #pragma unroll
        for (int j = 0; j < 4; ++j) {
            acc[j]     = ((const float*)&blo)[j];
            acc[4 + j] = ((const float*)&bhi)[j];
        }
        #pragma unroll
        for (int j = 0; j < 8; ++j) {
            const float w0 = (j < 4) ? ((const float*)&wlo[0])[j] : ((const float*)&whi[0])[j - 4];
            const float w1 = (j < 4) ? ((const float*)&wlo[1])[j] : ((const float*)&whi[1])[j - 4];
            const float w2 = (j < 4) ? ((const float*)&wlo[2])[j] : ((const float*)&whi[2])[j - 4];
            const float w3 = (j < 4) ? ((const float*)&wlo[3])[j] : ((const float*)&whi[3])[j - 4];
            acc[j] += w0 * bf2f(r0[j]) + w1 * bf2f(r1[j]) + w2 * bf2f(r2[j]) + w3 * bf2f(cur[j]);
        }
        short8v o;
        #pragma unroll
        for (int j = 0; j < 8; ++j)
            o[j] = f2bf(acc[j] * sigmoid_f(acc[j]));
        *(short8v*)(obase + (long)(l0 + i) * DINNER) = o;
        r0 = r1; r1 = r2; r2 = cur;
    }
}

// ---------------- chunk-parallel selective scan (bf16 activations) ----------------
__global__ __launch_bounds__(256) void scan_pass1_kernel(
    const __hip_bfloat16* __restrict__ delta, const __hip_bfloat16* __restrict__ xc,
    const __hip_bfloat16* __restrict__ dbc, const float* __restrict__ A2T,
    float* __restrict__ Fbuf, float* __restrict__ Dbuf)
{
    const int bx = blockIdx.x;             // mb(6) x cg(4) x chunk(64)
    const int chunk = bx & (NCHUNK - 1);
    const int cg = (bx >> 6) & 3;
    const int mb = bx >> 8;
    const int m = mb >> 1, b = mb & 1;
    const int tid = threadIdx.x;
    const int c = cg * 256 + tid;

    float A2[NSTATE];
    #pragma unroll
    for (int n = 0; n < NSTATE; ++n)
        A2[n] = A2T[((long)m * NSTATE + n) * DINNER + c];
    float h[NSTATE] = {};
    float sum_d = 0.f;

    __shared__ float sB[CHUNK][NSTATE];
    const short* dbc_mb = (const short*)dbc + (long)m * MROWS * 64 + (long)b * LSEQ * 64;
    const int t0 = chunk * CHUNK;
    for (int i = tid; i < CHUNK * NSTATE; i += 256) {
        int tt = i >> 4, j = i & 15;
        sB[tt][j] = bf2f(dbc_mb[(long)(t0 + tt) * 64 + 32 + j]);
    }
    __syncthreads();

    const short* dp = (const short*)delta;
    const short* up = (const short*)xc;
    const long base = ((long)mb * LSEQ + t0) * DINNER + c;
    #pragma unroll 4
    for (int tt = 0; tt < CHUNK; ++tt) {
        const float d = bf2f(dp[base + (long)tt * DINNER]);
        const float u = bf2f(up[base + (long)tt * DINNER]);
        const float du = d * u;
        sum_d += d;
        #pragma unroll
        for (int n = 0; n < NSTATE; ++n) {
            float e = EXP2F(d * A2[n]);
            h[n] = e * h[n] + du * sB[tt][n];
        }
    }
    const long ob = ((long)mb * NCHUNK + chunk) * (NSTATE * DINNER) + c;
    #pragma unroll
    for (int n = 0; n < NSTATE; ++n) {
        Fbuf[ob + n * DINNER] = h[n];
        Dbuf[ob + n * DINNER] = EXP2F(sum_d * A2[n]);
    }
}

__global__ __launch_bounds__(256) void scan_pass2_kernel(float* __restrict__ Fbuf,
                                                         const float* __restrict__ Dbuf)
{
    const long idx = (long)blockIdx.x * 256 + threadIdx.x;  // < 6*16*1024
    const int mb = (int)(idx >> 14);
    const int cn = (int)(idx & 16383);        // n*1024 + c
    float run = 0.f;
    for (int k = 0; k < NCHUNK; ++k) {
        const long o = ((long)(mb * NCHUNK + k) << 14) + cn;
        const float f = Fbuf[o];
        const float p = Dbuf[o];
        Fbuf[o] = run;
        run = p * run + f;
    }
}

__global__ __launch_bounds__(256) void scan_pass3_kernel(
    const __hip_bfloat16* __restrict__ delta, const __hip_bfloat16* __restrict__ xc,
    const __hip_bfloat16* __restrict__ dbc, __hip_bfloat16* __restrict__ xz,
    const float* __restrict__ A2T, const float* __restrict__ D_skip,
    const float* __restrict__ Hin)
{
    const int bx = blockIdx.x;
    const int chunk = bx & (NCHUNK - 1);
    const int cg = (bx >> 6) & 3;
    const int mb = bx >> 8;
    const int m = mb >> 1, b = mb & 1;
    const int tid = threadIdx.x;
    const int c = cg * 256 + tid;

    float A2[NSTATE];
    #pragma unroll
    for (int n = 0; n < NSTATE; ++n)
        A2[n] = A2T[((long)m * NSTATE + n) * DINNER + c];
    const float Dsk = D_skip[m * DINNER + c];

    float h[NSTATE];
    const long ho = ((long)mb * NCHUNK + chunk) * (NSTATE * DINNER) + c;
    #pragma unroll
    for (int n = 0; n < NSTATE; ++n) h[n] = Hin[ho + n * DINNER];

    __shared__ float sBC[CHUNK][2 * NSTATE];
    const short* dbc_mb = (const short*)dbc + (long)m * MROWS * 64 + (long)b * LSEQ * 64;
    const int t0 = chunk * CHUNK;
    for (int i = tid; i < CHUNK * 2 * NSTATE; i += 256) {
        int tt = i >> 5, j = i & 31;
        sBC[tt][j] = bf2f(dbc_mb[(long)(t0 + tt) * 64 + 32 + j]);
    }
    __syncthreads();

    const short* dp = (const short*)delta;
    const short* up = (const short*)xc;
    short* xzp = (short*)xz;
    const long base = ((long)mb * LSEQ + t0) * DINNER + c;
    const long xbase = ((long)mb * LSEQ + t0) * 2048 + c;
    #pragma unroll 4
    for (int tt = 0; tt < CHUNK; ++tt) {
        const long idx = base + (long)tt * DINNER;
        const long xi  = xbase + (long)tt * 2048;
        const float d = bf2f(dp[idx]);
        const float u = bf2f(up[idx]);
        const float zv = bf2f(xzp[xi + 1024]);
        const float du = d * u;
        float y = 0.f;
        #pragma unroll
        for (int n = 0; n < NSTATE; ++n) {
            float e = EXP2F(d * A2[n]);
            h[n] = e * h[n] + du * sBC[tt][n];
            y += h[n] * sBC[tt][16 + n];
        }
        y += u * Dsk;
        xzp[xi] = f2bf(y * (zv * sigmoid_f(zv)));
    }
}

extern "C" void kernel_launch(void* const* d_in, const int* in_sizes, int n_in,
                              void* d_out, int out_size, void* d_ws, size_t ws_size,
                              hipStream_t stream)
{
    const float* v       = (const float*)d_in[0];
    const float* a       = (const float*)d_in[1];
    const float* t       = (const float*)d_in[2];
    const float* norm_w  = (const float*)d_in[3];
    const float* norm_b  = (const float*)d_in[4];
    const float* in_w    = (const float*)d_in[5];
    const float* conv_w  = (const float*)d_in[6];
    const float* conv_b  = (const float*)d_in[7];
    const float* xproj_w = (const float*)d_in[8];
    const float* dt_w    = (const float*)d_in[9];
    const float* dt_b    = (const float*)d_in[10];
    const float* A_log   = (const float*)d_in[11];
    const float* D_skip  = (const float*)d_in[12];
    const float* out_w   = (const float*)d_in[13];
    const float* couple_w= (const float*)d_in[14];
    const float* coef    = (const float*)d_in[15];
    float* out = (float*)d_out;

    typedef __hip_bfloat16 bf;
    float* x_in   = (float*)d_ws;                       // [3][4096][512] f32
    bf* xn_bf     = (bf*)(x_in + 6291456);              // [3][4096][512]
    bf* sec_bf    = xn_bf + 6291456;                    // [3][4096][512]
    bf* xz_bf     = sec_bf + 6291456;                   // [3][4096][2048]  (xc-pre | z; later y | z)
    bf* xc_bf     = xz_bf + 25165824;                   // [3][4096][1024]
    bf* delta_bf  = xc_bf + 12582912;                   // [3][4096][1024]
    bf* dbc_bf    = delta_bf + 12582912;                // [3][4096][64]
    bf* cw_bf     = dbc_bf + 786432;                    // [3][512][512]
    bf* inw_bf    = cw_bf + 786432;                     // [3][2048][512]
    bf* xpw_bf    = inw_bf + 3145728;                   // [3][64][1024]
    bf* dtw_bf    = xpw_bf + 196608;                    // [3][1024][32]
    bf* outw_bf   = dtw_bf + 98304;                     // [3][512][1024]
    float* cwT    = (float*)(outw_bf + 1572864);        // [3][4][1024] f32
    float* A2T    = cwT + 12288;                        // [3][16][1024] f32
    float* Fbuf   = A2T + 49152;                        // [6][64][16][1024] f32

    float* Dbuf = out;                                  // [6][64][16][1024] — exactly out_size

    dim3 blk(256);

    // 0. prep: stack + weight conversions + conv-wT/A2T
    stack_vat_kernel<<<6144, blk, 0, stream>>>(v, a, t, x_in, sec_bf);
    cvt_all_kernel<<<(196608 + 786432 + 49152 + 24576 + 393216 + 255) / 256, blk, 0, stream>>>(
        couple_w, cw_bf, 196608, in_w, inw_bf, 786432, xproj_w, xpw_bf, 49152,
        dt_w, dtw_bf, 24576, out_w, outw_bf, 393216);
    small_prep_kernel<<<(12288 + 49152 + 255) / 256, blk, 0, stream>>>(conv_w, cwT, A_log, A2T);

    // 1. coupling: x_in += coef[z] * sec_bf @ cw^T
    gemm_bf16<4, 64><<<dim3(4, 32, 3), blk, 0, stream>>>(
        (bf*)sec_bf, cw_bf, 512, 512, 512, 2097152L, 262144L,
        x_in, nullptr, 512, 2097152L, x_in, 2097152L, coef, 1, nullptr, 0L, 0);
    // 2. layernorm -> bf16
    ln_kernel<<<3*4096, blk, 0, stream>>>(x_in, xn_bf, norm_w, norm_b);
    // 3. in_proj (both halves, N=2048) -> xz
    gemm_bf16<4, 64><<<dim3(16, 32, 3), blk, 0, stream>>>(
        xn_bf, inw_bf, 512, 512, 512, 2097152L, 1048576L,
        nullptr, xz_bf, 2048, 8388608L, nullptr, 0L, nullptr, 0, nullptr, 0L, 0);
    // 4. conv + SiLU (reads xz cols 0..1023)
    conv_silu_kernel<<<768, blk, 0, stream>>>(xz_bf, cwT, conv_b, xc_bf);
    // 5. x_proj -> dbc bf16
    gemm_bf16<2, 64><<<dim3(1, 32, 3), blk, 0, stream>>>(
        xc_bf, xpw_bf, 1024, 1024, 1024, 4194304L, 65536L,
        nullptr, dbc_bf, 64, 262144L, nullptr, 0L, nullptr, 0, nullptr, 0L, 0);
    // 6. delta = softplus(dt @ dt_w^T + dt_b) -> bf16
    gemm_bf16<4, 32><<<dim3(8, 32, 3), blk, 0, stream>>>(
        dbc_bf, dtw_bf, 32, 64, 32, 262144L, 32768L,
        nullptr, delta_bf, 1024, 4194304L, nullptr, 0L, nullptr, 0, dt_b, 1024L, 1);
    // 7. chunk-parallel scan
    scan_pass1_kernel<<<6*4*NCHUNK, blk, 0, stream>>>(delta_bf, xc_bf, dbc_bf, A2T, Fbuf, Dbuf);
    scan_pass2_kernel<<<(6*1024*16)/256, blk, 0, stream>>>(Fbuf, Dbuf);
    scan_pass3_kernel<<<6*4*NCHUNK, blk, 0, stream>>>(delta_bf, xc_bf, dbc_bf, xz_bf,
                                                      A2T, D_skip, Fbuf);
    // 8. out_proj + residual -> d_out (f32); A = y in xz cols 0..1023, lda 2048
    gemm_bf16<4, 64><<<dim3(4, 32, 3), blk, 0, stream>>>(
        xz_bf, outw_bf, 1024, 2048, 1024, 8388608L, 524288L,
        out, nullptr, 512, 2097152L, x_in, 2097152L, nullptr, 0, nullptr, 0L, 0);
}

// Round 8
// 307.819 us; speedup vs baseline: 7.1465x; 1.0481x over previous
//
#include <hip/hip_runtime.h>
#include <hip/hip_bf16.h>

#define MODS 3
#define BSZ 2
#define LSEQ 2048
#define DMODEL 512
#define DINNER 1024
#define DTRANK 32
#define NSTATE 16
#define DCONV 4
#define MROWS (BSZ*LSEQ)   // 4096
#define NCHUNK 64
#define CHUNK 32           // LSEQ / NCHUNK

#define LOG2E 1.44269504088896f
#define LN2   0.69314718055995f

typedef __attribute__((ext_vector_type(8))) short short8v;
typedef __attribute__((ext_vector_type(4))) short short4v;
typedef __attribute__((ext_vector_type(2))) short short2v;
typedef __attribute__((ext_vector_type(4))) float f32x4;

#if __has_builtin(__builtin_amdgcn_exp2f)
#define EXP2F __builtin_amdgcn_exp2f
#else
#define EXP2F exp2f
#endif
#if __has_builtin(__builtin_amdgcn_rcpf)
#define RCPF __builtin_amdgcn_rcpf
#else
#define RCPF(x) (1.0f / (x))
#endif

__device__ __forceinline__ short f2bf(float x) {
    __hip_bfloat16 h = __float2bfloat16(x);
    return __builtin_bit_cast(short, h);
}
__device__ __forceinline__ float bf2f(short s) {
    return __uint_as_float(((unsigned)(unsigned short)s) << 16);
}
__device__ __forceinline__ void gl_lds16(const short* g, short* l) {
    __builtin_amdgcn_global_load_lds(
        (const __attribute__((address_space(1))) unsigned int*)g,
        (__attribute__((address_space(3))) unsigned int*)l, 16, 0, 0);
}
__device__ __forceinline__ float sigmoid_f(float x) {
    return RCPF(1.f + EXP2F(-x * LOG2E));
}

// ---------------- bf16 MFMA GEMM NT, BK=32, XOR-swizzled LDS, 2-phase prefetch dbuf ----
// C[z] = res[z] + coef[z] * act(A[z] @ B[z]^T + bias[z])
// Tile 128 x (NJ*32). K % 32 == 0. LDS[r][s] = G[r][s ^ ((r>>1)&3)] (16B slots),
// achieved by pre-swizzling the per-lane GLOBAL source (dest stays linear for
// global_load_lds); reads apply the same XOR -> conflict-free ds_read_b128.
// K-loop: stage(next buf) BEFORE compute(cur), single barrier per tile.
template<int NJ>
__global__ __launch_bounds__(256) void gemm_bf16(
    const __hip_bfloat16* __restrict__ A_, const __hip_bfloat16* __restrict__ B_,
    int K, int lda, int ldb, long sA, long sB,
    float* __restrict__ Cf, __hip_bfloat16* __restrict__ Cb, int ldc, long sC,
    const float* __restrict__ res, long sRes,
    const float* __restrict__ coef_base, int coef_stride,
    const float* __restrict__ bias, long sBias, int act)
{
    constexpr int BK = 32;
    constexpr int BN = NJ * 32;
    constexpr int ASZ = 128 * BK;          // elems per A buffer
    constexpr int BSZe = BN * BK;          // elems per B buffer
    __shared__ alignas(16) short As[2 * ASZ];
    __shared__ alignas(16) short Bs[2 * BSZe];
    const int z = blockIdx.z;
    const int bm0 = blockIdx.y * 128;
    const int bn0 = blockIdx.x * BN;
    const short* Ag = (const short*)A_ + z * sA + (long)bm0 * lda;
    const short* Bg = (const short*)B_ + z * sB + (long)bn0 * ldb;
    const int tid = threadIdx.x;
    const int lane = tid & 63;
    const int w = tid >> 6;
    const int wr = w >> 1, wc = w & 1;
    const int lr = lane & 15;
    const int sidx = lane >> 4;                       // 16B slot 0..3
    const int srow = tid >> 2;                        // staging row 0..63
    const int sgcol = ((tid & 3) ^ ((srow >> 1) & 3)) * 8;   // swizzled global col
    const int fA = (lr >> 1) & 3;                     // read-side XOR

    constexpr int AINSTR = ASZ / 2048;                // 2
    constexpr int BINSTR = BSZe / 2048;               // NJ/2
    constexpr int RPI = 2048 / BK;                    // 64 rows per instr

    f32x4 acc[4][NJ];
    #pragma unroll
    for (int i = 0; i < 4; ++i)
        #pragma unroll
        for (int j = 0; j < NJ; ++j)
            acc[i][j] = (f32x4){0.f, 0.f, 0.f, 0.f};

    auto stage = [&](int buf, int k0) {
        #pragma unroll
        for (int i = 0; i < AINSTR; ++i)
            gl_lds16(Ag + (long)(i * RPI + srow) * lda + k0 + sgcol,
                     As + buf * ASZ + i * 2048 + tid * 8);
        #pragma unroll
        for (int i = 0; i < BINSTR; ++i)
            gl_lds16(Bg + (long)(i * RPI + srow) * ldb + k0 + sgcol,
                     Bs + buf * BSZe + i * 2048 + tid * 8);
    };
    auto compute = [&](int buf) {
        const int sl = (sidx ^ fA) * 8;
        short8v af[4], bfr[NJ];
        #pragma unroll
        for (int i = 0; i < 4; ++i)
            af[i] = *(const short8v*)&As[buf * ASZ + (wr * 64 + i * 16 + lr) * BK + sl];
        #pragma unroll
        for (int j = 0; j < NJ; ++j)
            bfr[j] = *(const short8v*)&Bs[buf * BSZe + (wc * NJ * 16 + j * 16 + lr) * BK + sl];
        #pragma unroll
        for (int i = 0; i < 4; ++i)
            #pragma unroll
            for (int j = 0; j < NJ; ++j)
                acc[i][j] = __builtin_amdgcn_mfma_f32_16x16x32_bf16(af[i], bfr[j], acc[i][j], 0, 0, 0);
    };

    // prologue
    stage(0, 0);
    __syncthreads();
    int cur = 0;
    for (int k0 = BK; k0 < K; k0 += BK) {
        stage(cur ^ 1, k0);        // prefetch next tile (in flight during compute)
        compute(cur);
        __syncthreads();           // drains vmcnt+lgkmcnt -> next tile ready, cur free
        cur ^= 1;
    }
    compute(cur);

    const float alpha = coef_base ? coef_base[z * coef_stride] : 1.0f;
    const float* resz = res ? res + z * sRes : nullptr;
    const float* biasz = bias ? bias + z * sBias : nullptr;
    float* Cfz = Cf ? Cf + z * sC : nullptr;
    __hip_bfloat16* Cbz = Cb ? Cb + z * sC : nullptr;
    #pragma unroll
    for (int i = 0; i < 4; ++i) {
        #pragma unroll
        for (int r = 0; r < 4; ++r) {
            const int row = bm0 + wr * 64 + i * 16 + (lane >> 4) * 4 + r;
            #pragma unroll
            for (int j = 0; j < NJ; ++j) {
                const int col = bn0 + wc * NJ * 16 + j * 16 + lr;
                float val = acc[i][j][r];
                if (biasz) val += biasz[col];
                if (act == 1)
                    val = (val > 20.f) ? val : LN2 * __log2f(1.f + EXP2F(val * LOG2E));
                val *= alpha;
                if (resz) val += resz[(long)row * ldc + col];
                if (Cfz) Cfz[(long)row * ldc + col] = val;
                else     Cbz[(long)row * ldc + col] = __float2bfloat16(val);
            }
        }
    }
}

// ---------------- stack: x_in = [v;a;t] f32, sec_bf = [a;t;v] bf16 ----------------
__global__ __launch_bounds__(256) void stack_vat_kernel(
    const float* __restrict__ v, const float* __restrict__ a, const float* __restrict__ t,
    float* __restrict__ x_in, __hip_bfloat16* __restrict__ sec_bf)
{
    const long idx = (long)blockIdx.x * 256 + threadIdx.x;
    const int m = (int)(idx >> 19);
    const long off = idx & 524287;
    const float* prim = (m == 0) ? v : (m == 1) ? a : t;
    const float* sec  = (m == 0) ? a : (m == 1) ? t : v;
    float4 pv = ((const float4*)prim)[off];
    float4 sv = ((const float4*)sec)[off];
    ((float4*)x_in)[idx] = pv;
    short4v s;
    s.x = f2bf(sv.x); s.y = f2bf(sv.y); s.z = f2bf(sv.z); s.w = f2bf(sv.w);
    ((short4v*)sec_bf)[idx] = s;
}

// ---------------- fused weight conversions: 5 segments f32 -> bf16 ----------------
__global__ __launch_bounds__(256) void cvt_all_kernel(
    const float* __restrict__ s0, __hip_bfloat16* __restrict__ d0, int n0,
    const float* __restrict__ s1, __hip_bfloat16* __restrict__ d1, int n1,
    const float* __restrict__ s2, __hip_bfloat16* __restrict__ d2, int n2,
    const float* __restrict__ s3, __hip_bfloat16* __restrict__ d3, int n3,
    const float* __restrict__ s4, __hip_bfloat16* __restrict__ d4, int n4)
{
    int idx = blockIdx.x * 256 + threadIdx.x;
    const float* s; __hip_bfloat16* d; int off = idx;
    if      (off < n0)                  { s = s0; d = d0; }
    else if ((off -= n0) < n1)          { s = s1; d = d1; }
    else if ((off -= n1) < n2)          { s = s2; d = d2; }
    else if ((off -= n2) < n3)          { s = s3; d = d3; }
    else if ((off -= n3) < n4)          { s = s4; d = d4; }
    else return;
    float4 vv = ((const float4*)s)[off];
    short4v o;
    o.x = f2bf(vv.x); o.y = f2bf(vv.y); o.z = f2bf(vv.z); o.w = f2bf(vv.w);
    ((short4v*)d)[off] = o;
}

// ---------------- small prep: conv-weight transpose + A2T ----------------
__global__ __launch_bounds__(256) void small_prep_kernel(const float* __restrict__ cw,
    float* __restrict__ cwT, const float* __restrict__ A_log, float* __restrict__ A2T)
{
    const int idx = blockIdx.x * 256 + threadIdx.x;
    if (idx < MODS * DINNER * DCONV) {
        const int k = idx & 3;
        const int c = (idx >> 2) & 1023;
        const int m = idx >> 12;
        cwT[(m * DCONV + k) * DINNER + c] = cw[idx];
    } else if (idx < MODS * DINNER * DCONV + MODS * NSTATE * DINNER) {
        const int j = idx - MODS * DINNER * DCONV;
        const int c = j & 1023;
        const int n = (j >> 10) & 15;
        const int m = j >> 14;
        A2T[j] = -EXP2F(A_log[((long)m * DINNER + c) * NSTATE + n] * LOG2E) * LOG2E;
    }
}

// ---------------- LayerNorm: f32 in -> bf16 out ----------------
__global__ __launch_bounds__(256) void ln_kernel(const float* __restrict__ x, __hip_bfloat16* __restrict__ xn,
                                                 const float* __restrict__ nw, const float* __restrict__ nb)
{
    const int row = blockIdx.x;
    const int m = row >> 12;
    const int tid = threadIdx.x;
    const float2 v = *reinterpret_cast<const float2*>(x + (long)row * DMODEL + tid * 2);
    float s = v.x + v.y;
    float sq = v.x * v.x + v.y * v.y;
    #pragma unroll
    for (int off = 32; off > 0; off >>= 1) {
        s  += __shfl_down(s, off);
        sq += __shfl_down(sq, off);
    }
    __shared__ float ws_s[4], ws_q[4];
    const int wid = tid >> 6, lane = tid & 63;
    if (lane == 0) { ws_s[wid] = s; ws_q[wid] = sq; }
    __syncthreads();
    if (tid == 0) {
        float ts = ws_s[0] + ws_s[1] + ws_s[2] + ws_s[3];
        float tq = ws_q[0] + ws_q[1] + ws_q[2] + ws_q[3];
        float mu = ts / DMODEL;
        float var = tq / DMODEL - mu * mu;
        ws_s[0] = mu;
        ws_q[0] = rsqrtf(var + 1e-5f);
    }
    __syncthreads();
    const float mu = ws_s[0], rstd = ws_q[0];
    const int e0 = tid * 2;
    float2 w  = *reinterpret_cast<const float2*>(nw + m * DMODEL + e0);
    float2 bb = *reinterpret_cast<const float2*>(nb + m * DMODEL + e0);
    short2v o;
    o.x = f2bf((v.x - mu) * rstd * w.x + bb.x);
    o.y = f2bf((v.y - mu) * rstd * w.y + bb.y);
    *reinterpret_cast<short2v*>((short*)xn + (long)row * DMODEL + e0) = o;
}

// ---------------- depthwise causal conv(4) + SiLU ----------------
__global__ __launch_bounds__(256) void conv_silu_kernel(const __hip_bfloat16* __restrict__ xz,
    const float* __restrict__ cwT, const float* __restrict__ cb, __hip_bfloat16* __restrict__ xc)
{
    const int idx = blockIdx.x * 256 + threadIdx.x;   // < 6*256*128 = 196608
    const int c8 = idx & 127;
    const int lt = (idx >> 7) & 255;
    const int mb = idx >> 15;
    const int m  = mb >> 1;
    const int c0 = c8 * 8;
    const int l0 = lt * 8;

    float4 wlo[DCONV], whi[DCONV];
    #pragma unroll
    for (int k = 0; k < DCONV; ++k) {
        wlo[k] = *(const float4*)&cwT[(m * DCONV + k) * DINNER + c0];
        whi[k] = *(const float4*)&cwT[(m * DCONV + k) * DINNER + c0 + 4];
    }
    const float4 blo = *(const float4*)&cb[m * DINNER + c0];
    const float4 bhi = *(const float4*)&cb[m * DINNER + c0 + 4];

    const short* base = (const short*)xz + (long)mb * LSEQ * 2048 + c0;
    short* obase = (short*)xc + (long)mb * LSEQ * DINNER + c0;

    short8v r0 = {}, r1 = {}, r2 = {};
    if (l0 - 3 >= 0) r0 = *(const short8v*)(base + (long)(l0 - 3) * 2048);
    if (l0 - 2 >= 0) r1 = *(const short8v*)(base + (long)(l0 - 2) * 2048);
    if (l0 - 1 >= 0) r2 = *(const short8v*)(base + (long)(l0 - 1) * 2048);

    #pragma unroll
    for (int i = 0; i < 8; ++i) {
        const short8v cur = *(const short8v*)(base + (long)(l0 + i) * 2048);
        float acc[8];
        #pragma unroll
        for (int j = 0; j < 4; ++j) {
            acc[j]     = ((const float*)&blo)[j];
            acc[4 + j] = ((const float*)&bhi)[j];
        }
        #pragma unroll
        for (int j = 0; j < 8; ++j) {
            const float w0 = (j < 4) ? ((const float*)&wlo[0])[j] : ((const float*)&whi[0])[j - 4];
            const float w1 = (j < 4) ? ((const float*)&wlo[1])[j] : ((const float*)&whi[1])[j - 4];
            const float w2 = (j < 4) ? ((const float*)&wlo[2])[j] : ((const float*)&whi[2])[j - 4];
            const float w3 = (j < 4) ? ((const float*)&wlo[3])[j] : ((const float*)&whi[3])[j - 4];
            acc[j] += w0 * bf2f(r0[j]) + w1 * bf2f(r1[j]) + w2 * bf2f(r2[j]) + w3 * bf2f(cur[j]);
        }
        short8v o;
        #pragma unroll
        for (int j = 0; j < 8; ++j)
            o[j] = f2bf(acc[j] * sigmoid_f(acc[j]));
        *(short8v*)(obase + (long)(l0 + i) * DINNER) = o;
        r0 = r1; r1 = r2; r2 = cur;
    }
}

// ---------------- chunk-parallel selective scan (bf16 activations) ----------------
__global__ __launch_bounds__(256) void scan_pass1_kernel(
    const __hip_bfloat16* __restrict__ delta, const __hip_bfloat16* __restrict__ xc,
    const __hip_bfloat16* __restrict__ dbc, const float* __restrict__ A2T,
    float* __restrict__ Fbuf, float* __restrict__ Dbuf)
{
    const int bx = blockIdx.x;             // mb(6) x cg(4) x chunk(64)
    const int chunk = bx & (NCHUNK - 1);
    const int cg = (bx >> 6) & 3;
    const int mb = bx >> 8;
    const int m = mb >> 1, b = mb & 1;
    const int tid = threadIdx.x;
    const int c = cg * 256 + tid;

    float A2[NSTATE];
    #pragma unroll
    for (int n = 0; n < NSTATE; ++n)
        A2[n] = A2T[((long)m * NSTATE + n) * DINNER + c];
    float h[NSTATE] = {};
    float sum_d = 0.f;

    __shared__ float sB[CHUNK][NSTATE];
    const short* dbc_mb = (const short*)dbc + (long)m * MROWS * 64 + (long)b * LSEQ * 64;
    const int t0 = chunk * CHUNK;
    for (int i = tid; i < CHUNK * NSTATE; i += 256) {
        int tt = i >> 4, j = i & 15;
        sB[tt][j] = bf2f(dbc_mb[(long)(t0 + tt) * 64 + 32 + j]);
    }
    __syncthreads();

    const short* dp = (const short*)delta;
    const short* up = (const short*)xc;
    const long base = ((long)mb * LSEQ + t0) * DINNER + c;
    #pragma unroll 4
    for (int tt = 0; tt < CHUNK; ++tt) {
        const float d = bf2f(dp[base + (long)tt * DINNER]);
        const float u = bf2f(up[base + (long)tt * DINNER]);
        const float du = d * u;
        sum_d += d;
        #pragma unroll
        for (int n = 0; n < NSTATE; ++n) {
            float e = EXP2F(d * A2[n]);
            h[n] = e * h[n] + du * sB[tt][n];
        }
    }
    const long ob = ((long)mb * NCHUNK + chunk) * (NSTATE * DINNER) + c;
    #pragma unroll
    for (int n = 0; n < NSTATE; ++n) {
        Fbuf[ob + n * DINNER] = h[n];
        Dbuf[ob + n * DINNER] = EXP2F(sum_d * A2[n]);
    }
}

__global__ __launch_bounds__(256) void scan_pass2_kernel(float* __restrict__ Fbuf,
                                                         const float* __restrict__ Dbuf)
{
    const long idx = (long)blockIdx.x * 256 + threadIdx.x;  // < 6*16*1024
    const int mb = (int)(idx >> 14);
    const int cn = (int)(idx & 16383);        // n*1024 + c
    float run = 0.f;
    for (int k = 0; k < NCHUNK; ++k) {
        const long o = ((long)(mb * NCHUNK + k) << 14) + cn;
        const float f = Fbuf[o];
        const float p = Dbuf[o];
        Fbuf[o] = run;
        run = p * run + f;
    }
}

__global__ __launch_bounds__(256) void scan_pass3_kernel(
    const __hip_bfloat16* __restrict__ delta, const __hip_bfloat16* __restrict__ xc,
    const __hip_bfloat16* __restrict__ dbc, __hip_bfloat16* __restrict__ xz,
    const float* __restrict__ A2T, const float* __restrict__ D_skip,
    const float* __restrict__ Hin)
{
    const int bx = blockIdx.x;
    const int chunk = bx & (NCHUNK - 1);
    const int cg = (bx >> 6) & 3;
    const int mb = bx >> 8;
    const int m = mb >> 1, b = mb & 1;
    const int tid = threadIdx.x;
    const int c = cg * 256 + tid;

    float A2[NSTATE];
    #pragma unroll
    for (int n = 0; n < NSTATE; ++n)
        A2[n] = A2T[((long)m * NSTATE + n) * DINNER + c];
    const float Dsk = D_skip[m * DINNER + c];

    float h[NSTATE];
    const long ho = ((long)mb * NCHUNK + chunk) * (NSTATE * DINNER) + c;
    #pragma unroll
    for (int n = 0; n < NSTATE; ++n) h[n] = Hin[ho + n * DINNER];

    __shared__ float sBC[CHUNK][2 * NSTATE];
    const short* dbc_mb = (const short*)dbc + (long)m * MROWS * 64 + (long)b * LSEQ * 64;
    const int t0 = chunk * CHUNK;
    for (int i = tid; i < CHUNK * 2 * NSTATE; i += 256) {
        int tt = i >> 5, j = i & 31;
        sBC[tt][j] = bf2f(dbc_mb[(long)(t0 + tt) * 64 + 32 + j]);
    }
    __syncthreads();

    const short* dp = (const short*)delta;
    const short* up = (const short*)xc;
    short* xzp = (short*)xz;
    const long base = ((long)mb * LSEQ + t0) * DINNER + c;
    const long xbase = ((long)mb * LSEQ + t0) * 2048 + c;
    #pragma unroll 4
    for (int tt = 0; tt < CHUNK; ++tt) {
        const long idx = base + (long)tt * DINNER;
        const long xi  = xbase + (long)tt * 2048;
        const float d = bf2f(dp[idx]);
        const float u = bf2f(up[idx]);
        const float zv = bf2f(xzp[xi + 1024]);
        const float du = d * u;
        float y = 0.f;
        #pragma unroll
        for (int n = 0; n < NSTATE; ++n) {
            float e = EXP2F(d * A2[n]);
            h[n] = e * h[n] + du * sBC[tt][n];
            y += h[n] * sBC[tt][16 + n];
        }
        y += u * Dsk;
        xzp[xi] = f2bf(y * (zv * sigmoid_f(zv)));
    }
}

extern "C" void kernel_launch(void* const* d_in, const int* in_sizes, int n_in,
                              void* d_out, int out_size, void* d_ws, size_t ws_size,
                              hipStream_t stream)
{
    const float* v       = (const float*)d_in[0];
    const float* a       = (const float*)d_in[1];
    const float* t       = (const float*)d_in[2];
    const float* norm_w  = (const float*)d_in[3];
    const float* norm_b  = (const float*)d_in[4];
    const float* in_w    = (const float*)d_in[5];
    const float* conv_w  = (const float*)d_in[6];
    const float* conv_b  = (const float*)d_in[7];
    const float* xproj_w = (const float*)d_in[8];
    const float* dt_w    = (const float*)d_in[9];
    const float* dt_b    = (const float*)d_in[10];
    const float* A_log   = (const float*)d_in[11];
    const float* D_skip  = (const float*)d_in[12];
    const float* out_w   = (const float*)d_in[13];
    const float* couple_w= (const float*)d_in[14];
    const float* coef    = (const float*)d_in[15];
    float* out = (float*)d_out;

    typedef __hip_bfloat16 bf;
    float* x_in   = (float*)d_ws;                       // [3][4096][512] f32
    bf* xn_bf     = (bf*)(x_in + 6291456);              // [3][4096][512]
    bf* sec_bf    = xn_bf + 6291456;                    // [3][4096][512]
    bf* xz_bf     = sec_bf + 6291456;                   // [3][4096][2048]  (xc-pre | z; later y | z)
    bf* xc_bf     = xz_bf + 25165824;                   // [3][4096][1024]
    bf* delta_bf  = xc_bf + 12582912;                   // [3][4096][1024]
    bf* dbc_bf    = delta_bf + 12582912;                // [3][4096][64]
    bf* cw_bf     = dbc_bf + 786432;                    // [3][512][512]
    bf* inw_bf    = cw_bf + 786432;                     // [3][2048][512]
    bf* xpw_bf    = inw_bf + 3145728;                   // [3][64][1024]
    bf* dtw_bf    = xpw_bf + 196608;                    // [3][1024][32]
    bf* outw_bf   = dtw_bf + 98304;                     // [3][512][1024]
    float* cwT    = (float*)(outw_bf + 1572864);        // [3][4][1024] f32
    float* A2T    = cwT + 12288;                        // [3][16][1024] f32
    float* Fbuf   = A2T + 49152;                        // [6][64][16][1024] f32

    float* Dbuf = out;                                  // [6][64][16][1024] — exactly out_size

    dim3 blk(256);

    // 0. prep: stack + weight conversions + conv-wT/A2T
    stack_vat_kernel<<<6144, blk, 0, stream>>>(v, a, t, x_in, sec_bf);
    cvt_all_kernel<<<(196608 + 786432 + 49152 + 24576 + 393216 + 255) / 256, blk, 0, stream>>>(
        couple_w, cw_bf, 196608, in_w, inw_bf, 786432, xproj_w, xpw_bf, 49152,
        dt_w, dtw_bf, 24576, out_w, outw_bf, 393216);
    small_prep_kernel<<<(12288 + 49152 + 255) / 256, blk, 0, stream>>>(conv_w, cwT, A_log, A2T);

    // 1. coupling: x_in += coef[z] * sec_bf @ cw^T  (NJ=2 -> 768 blocks)
    gemm_bf16<2><<<dim3(8, 32, 3), blk, 0, stream>>>(
        (bf*)sec_bf, cw_bf, 512, 512, 512, 2097152L, 262144L,
        x_in, nullptr, 512, 2097152L, x_in, 2097152L, coef, 1, nullptr, 0L, 0);
    // 2. layernorm -> bf16
    ln_kernel<<<3*4096, blk, 0, stream>>>(x_in, xn_bf, norm_w, norm_b);
    // 3. in_proj (both halves, N=2048) -> xz
    gemm_bf16<4><<<dim3(16, 32, 3), blk, 0, stream>>>(
        xn_bf, inw_bf, 512, 512, 512, 2097152L, 1048576L,
        nullptr, xz_bf, 2048, 8388608L, nullptr, 0L, nullptr, 0, nullptr, 0L, 0);
    // 4. conv + SiLU (reads xz cols 0..1023)
    conv_silu_kernel<<<768, blk, 0, stream>>>(xz_bf, cwT, conv_b, xc_bf);
    // 5. x_proj -> dbc bf16
    gemm_bf16<2><<<dim3(1, 32, 3), blk, 0, stream>>>(
        xc_bf, xpw_bf, 1024, 1024, 1024, 4194304L, 65536L,
        nullptr, dbc_bf, 64, 262144L, nullptr, 0L, nullptr, 0, nullptr, 0L, 0);
    // 6. delta = softplus(dt @ dt_w^T + dt_b) -> bf16 (K=32: single-tile path)
    gemm_bf16<4><<<dim3(8, 32, 3), blk, 0, stream>>>(
        dbc_bf, dtw_bf, 32, 64, 32, 262144L, 32768L,
        nullptr, delta_bf, 1024, 4194304L, nullptr, 0L, nullptr, 0, dt_b, 1024L, 1);
    // 7. chunk-parallel scan
    scan_pass1_kernel<<<6*4*NCHUNK, blk, 0, stream>>>(delta_bf, xc_bf, dbc_bf, A2T, Fbuf, Dbuf);
    scan_pass2_kernel<<<(6*1024*16)/256, blk, 0, stream>>>(Fbuf, Dbuf);
    scan_pass3_kernel<<<6*4*NCHUNK, blk, 0, stream>>>(delta_bf, xc_bf, dbc_bf, xz_bf,
                                                      A2T, D_skip, Fbuf);
    // 8. out_proj + residual -> d_out (f32); A = y in xz cols 0..1023, lda 2048 (NJ=2)
    gemm_bf16<2><<<dim3(8, 32, 3), blk, 0, stream>>>(
        xz_bf, outw_bf, 1024, 2048, 1024, 8388608L, 524288L,
        out, nullptr, 512, 2097152L, x_in, 2097152L, nullptr, 0, nullptr, 0L, 0);
}